// Round 9
// baseline (435.770 us; speedup 1.0000x reference)
//
#include <hip/hip_runtime.h>
#include <hip/hip_bf16.h>

typedef short s16x8 __attribute__((ext_vector_type(8)));
typedef float f32x4 __attribute__((ext_vector_type(4)));

#define C2 1536

__device__ __forceinline__ float b2f(ushort u){ return __uint_as_float(((unsigned)u)<<16); }
__device__ __forceinline__ ushort f2b(float f){ unsigned u = __float_as_uint(f); return (ushort)((u + 0x7fffu + ((u>>16)&1u)) >> 16); }

// async global -> LDS, 16B per lane at wave-uniform LDS base + lane*16
#define GL16(g, l) __builtin_amdgcn_global_load_lds( \
    (const __attribute__((address_space(1))) void*)(g), \
    (__attribute__((address_space(3))) void*)(l), 16, 0, 0)

#define VMW(n) asm volatile("s_waitcnt vmcnt(" #n ")" ::: "memory")
#define LGW()  asm volatile("s_waitcnt lgkmcnt(0)" ::: "memory")
#define SB()   __builtin_amdgcn_sched_barrier(0)
#define BAR()  __builtin_amdgcn_s_barrier()
#define SP1    __builtin_amdgcn_s_setprio(1)
#define SP0    __builtin_amdgcn_s_setprio(0)
#define MF(va, vb, c) __builtin_amdgcn_mfma_f32_16x16x32_bf16(va, vb, c, 0,0,0)

// ======================= 256x256 8-phase bf16 GEMM (verified R3-R8) =======================
// Used only for MLP GEMM1 (M=4096,N=3072,K=768; 192 blocks). See R3 notes.
#define RDA(P, mh) { const int ab = (P) + aro + (mh)*4096; \
    a0=L8(ab+sx0);      a1=L8(ab+sx1); \
    a2=L8(ab+1024+sx0); a3=L8(ab+1024+sx1); \
    a4=L8(ab+2048+sx0); a5=L8(ab+2048+sx1); \
    a6=L8(ab+3072+sx0); a7=L8(ab+3072+sx1); }
#define RDB0(P, nh) { const int bb = (P) + bro + (nh)*2048; \
    b00=L8(bb+sx0); b01=L8(bb+sx1); b02=L8(bb+1024+sx0); b03=L8(bb+1024+sx1); }
#define RDB1(P, nh) { const int bb = (P) + bro + (nh)*2048; \
    b10=L8(bb+sx0); b11=L8(bb+sx1); b12=L8(bb+1024+sx0); b13=L8(bb+1024+sx1); }
#define L8(off) (*(const s16x8*)&lds[off])
#define STG(p0, p1, T, dstb) { \
    GL16((p0) + (size_t)(T)*64, &lds[(dstb) + ldsw]); \
    GL16((p1) + (size_t)(T)*64, &lds[(dstb) + 4096 + ldsw]); }
#define QD(mh, nh, B0,B1,B2,B3) { \
  acc[(mh)*4+0][(nh)*2+0]=MF(a0,B0,acc[(mh)*4+0][(nh)*2+0]); \
  acc[(mh)*4+0][(nh)*2+0]=MF(a1,B1,acc[(mh)*4+0][(nh)*2+0]); \
  acc[(mh)*4+0][(nh)*2+1]=MF(a0,B2,acc[(mh)*4+0][(nh)*2+1]); \
  acc[(mh)*4+0][(nh)*2+1]=MF(a1,B3,acc[(mh)*4+0][(nh)*2+1]); \
  acc[(mh)*4+1][(nh)*2+0]=MF(a2,B0,acc[(mh)*4+1][(nh)*2+0]); \
  acc[(mh)*4+1][(nh)*2+0]=MF(a3,B1,acc[(mh)*4+1][(nh)*2+0]); \
  acc[(mh)*4+1][(nh)*2+1]=MF(a2,B2,acc[(mh)*4+1][(nh)*2+1]); \
  acc[(mh)*4+1][(nh)*2+1]=MF(a3,B3,acc[(mh)*4+1][(nh)*2+1]); \
  acc[(mh)*4+2][(nh)*2+0]=MF(a4,B0,acc[(mh)*4+2][(nh)*2+0]); \
  acc[(mh)*4+2][(nh)*2+0]=MF(a5,B1,acc[(mh)*4+2][(nh)*2+0]); \
  acc[(mh)*4+2][(nh)*2+1]=MF(a4,B2,acc[(mh)*4+2][(nh)*2+1]); \
  acc[(mh)*4+2][(nh)*2+1]=MF(a5,B3,acc[(mh)*4+2][(nh)*2+1]); \
  acc[(mh)*4+3][(nh)*2+0]=MF(a6,B0,acc[(mh)*4+3][(nh)*2+0]); \
  acc[(mh)*4+3][(nh)*2+0]=MF(a7,B1,acc[(mh)*4+3][(nh)*2+0]); \
  acc[(mh)*4+3][(nh)*2+1]=MF(a6,B2,acc[(mh)*4+3][(nh)*2+1]); \
  acc[(mh)*4+3][(nh)*2+1]=MF(a7,B3,acc[(mh)*4+3][(nh)*2+1]); }

#define EIGHT(t0, t1, DS, VM4) \
  /*P0*/ VMW(4); BAR(); \
  RDA(0,0); RDB0(0,0); \
  STG(pA00,pA01,(t1), 16384); \
  LGW(); SB(); SP1; QD(0,0,b00,b01,b02,b03); SP0; BAR(); \
  /*P1*/ RDB1(0,1); \
  STG(pA10,pA11,(t1), 24576); \
  BAR(); LGW(); SB(); SP1; QD(0,1,b10,b11,b12,b13); SP0; BAR(); \
  /*P2*/ RDA(0,1); \
  if (DS) { STG(pB00,pB01,(t0)+2, 32768); } \
  BAR(); LGW(); SB(); SP1; QD(1,0,b00,b01,b02,b03); SP0; BAR(); \
  /*P3*/ if (DS) { STG(pB10,pB11,(t0)+2, 40960); } \
  BAR(); SP1; QD(1,1,b10,b11,b12,b13); SP0; BAR(); \
  /*P4*/ VM4; BAR(); \
  RDA(16384,0); RDB0(16384,0); \
  if (DS) { STG(pA00,pA01,(t0)+2, 0); } \
  LGW(); SB(); SP1; QD(0,0,b00,b01,b02,b03); SP0; BAR(); \
  /*P5*/ RDB1(16384,1); \
  if (DS) { STG(pA10,pA11,(t0)+2, 8192); } \
  BAR(); LGW(); SB(); SP1; QD(0,1,b10,b11,b12,b13); SP0; BAR(); \
  /*P6*/ RDA(16384,1); \
  if (DS) { STG(pB00,pB01,(t1)+2, 49152); } \
  BAR(); LGW(); SB(); SP1; QD(1,0,b00,b01,b02,b03); SP0; BAR(); \
  /*P7*/ if (DS) { STG(pB10,pB11,(t1)+2, 57344); } \
  BAR(); SP1; QD(1,1,b10,b11,b12,b13); SP0; BAR();

template<int EPI>
__global__ __launch_bounds__(512, 1) void gemm256(
    const ushort* __restrict__ A, const ushort* __restrict__ BT,
    int M, int N, int K,
    const float* __restrict__ bias,
    ushort* __restrict__ o16, ushort* __restrict__ o16b)
{
    extern __shared__ ushort lds[];
    const int t = threadIdx.x;
    const int lane = t & 63, wv = t >> 6;
    const int wr = wv >> 2, wc = wv & 3;
    const int r0 = lane & 15, q = lane >> 4, e7 = lane & 7;
    const int m0 = blockIdx.y*256, n0 = blockIdx.x*256;

    const int idx = wv*64 + lane;
    const int lr8 = idx >> 3;
    const int ksrc = (idx & 7) ^ (lr8 & 7);
    const ushort* pA00 = A  + (size_t)(m0 +   0 +  0 + lr8)*K + ksrc*8;
    const ushort* pA01 = A  + (size_t)(m0 +   0 + 64 + lr8)*K + ksrc*8;
    const ushort* pA10 = A  + (size_t)(m0 + 128 +  0 + lr8)*K + ksrc*8;
    const ushort* pA11 = A  + (size_t)(m0 + 128 + 64 + lr8)*K + ksrc*8;
    const ushort* pB00 = BT + (size_t)(n0 +   0 +  0 + lr8)*K + ksrc*8;
    const ushort* pB01 = BT + (size_t)(n0 +   0 + 64 + lr8)*K + ksrc*8;
    const ushort* pB10 = BT + (size_t)(n0 + 128 +  0 + lr8)*K + ksrc*8;
    const ushort* pB11 = BT + (size_t)(n0 + 128 + 64 + lr8)*K + ksrc*8;
    const int ldsw = wv*512;

    const int aro = (wr*128 + r0)*64;
    const int bro = 32768 + (wc*64 + r0)*64;
    const int sx0 = (q ^ e7)*8, sx1 = ((q ^ e7)*8) ^ 32;

    f32x4 acc[8][4];
    #pragma unroll
    for (int i=0;i<8;++i)
        #pragma unroll
        for (int j=0;j<4;++j) acc[i][j] = (f32x4){0.f,0.f,0.f,0.f};
    s16x8 a0,a1,a2,a3,a4,a5,a6,a7;
    s16x8 b00,b01,b02,b03, b10,b11,b12,b13;

    const int nkt = K >> 6;
    const int niter = nkt >> 1;

    STG(pB00,pB01, 0, 32768);
    STG(pB10,pB11, 0, 40960);
    STG(pA00,pA01, 0, 0);
    STG(pA10,pA11, 0, 8192);
    STG(pB00,pB01, 1, 49152);
    STG(pB10,pB11, 1, 57344);

    for (int i = 0; i < niter-1; ++i) {
        const int t0 = 2*i, t1 = 2*i+1;
        EIGHT(t0, t1, 1, VMW(4));
    }
    {
        const int t0 = nkt-2, t1 = nkt-1;
        EIGHT(t0, t1, 0, VMW(0));
    }

    #pragma unroll
    for (int gm=0; gm<8; ++gm) {
        #pragma unroll
        for (int gn=0; gn<4; ++gn) {
            int col = n0 + wc*64 + gn*16 + r0;
            #pragma unroll
            for (int r=0; r<4; ++r) {
                int row = m0 + wr*128 + gm*16 + q*4 + r;
                float v = acc[gm][gn][r];
                if (EPI == 0) {
                    o16[(size_t)row*N + col] = f2b(v + bias[col]);
                } else {
                    v += bias[col];
                    float g = 0.5f*v*(1.0f + erff(v*0.70710678118f));
                    if (col < C2) o16 [(size_t)row*C2 + col]        = f2b(g);
                    else          o16b[(size_t)row*C2 + (col - C2)] = f2b(g);
                }
            }
        }
    }
}

// ---------------- 128x128 bf16 MFMA GEMM (R0 reg-staged, distance-2 prefetch) ----------------
// Split-K aware: K is the CHUNK length; block reads cols [blockIdx.z*K, (blockIdx.z+1)*K).
// EPI 0: V-projection with FUSED rope-reduce; linear in V so split-K safe (kz=0 carries bias).
// EPI 4: o16[row*2304 + 768 + col] = bf16(acc)      (Wfold2 -> BTf right; z=1)
// EPI 6: partial[row*768+col] = acc (f32), partial = (z ? o32b : o32)  (final GEMM split-K)
template<int EPI>
__global__ __launch_bounds__(256) void gemm_bf16(
    const ushort* __restrict__ A, const ushort* __restrict__ BT,
    int M, int N, int K, int lda, int ldbt,
    const float* __restrict__ bias,
    const float* __restrict__ w1tp, const float* __restrict__ w2tp, float* __restrict__ vsump,
    ushort* __restrict__ o16, float* __restrict__ o32, float* __restrict__ o32b)
{
    __shared__ ushort Al[2][128*32];
    __shared__ ushort Bl[2][128*32];
    const int t = threadIdx.x;
    const int m0 = blockIdx.y*128, n0 = blockIdx.x*128;
    const int koff = blockIdx.z * K;
    const int lane = t & 63, wv = t >> 6;
    const int wm = (wv>>1)*64, wn = (wv&1)*64;
    const int r0 = lane & 15, q = lane >> 4;

    const int c0i = t, c1i = t + 256;
    const int lrow0 = ((c0i>>6)<<4) | (c0i&15), lkc0 = ((c0i>>4)&3) << 3;
    const int lrow1 = ((c1i>>6)<<4) | (c1i&15), lkc1 = ((c1i>>4)&3) << 3;
    const ushort* gA0 = A  + (size_t)(m0+lrow0)*lda + koff + lkc0;
    const ushort* gB0 = BT + (size_t)(n0+lrow0)*ldbt + koff + lkc0;
    const ushort* gA1 = A  + (size_t)(m0+lrow1)*lda + koff + lkc1;
    const ushort* gB1 = BT + (size_t)(n0+lrow1)*ldbt + koff + lkc1;

    f32x4 acc[4][4];
    #pragma unroll
    for (int i=0;i<4;++i)
        #pragma unroll
        for (int j=0;j<4;++j) acc[i][j] = (f32x4){0.f,0.f,0.f,0.f};

    const int nkt = K >> 5;
    uint4 pa0_0, pb0_0, pa1_0, pb1_0;
    uint4 pa0_1, pb0_1, pa1_1, pb1_1;
    pa0_0 = *(const uint4*)gA0;        pb0_0 = *(const uint4*)gB0;
    pa1_0 = *(const uint4*)gA1;        pb1_0 = *(const uint4*)gB1;
    pa0_1 = *(const uint4*)(gA0 + 32); pb0_1 = *(const uint4*)(gB0 + 32);
    pa1_1 = *(const uint4*)(gA1 + 32); pb1_1 = *(const uint4*)(gB1 + 32);
    *(uint4*)&Al[0][c0i*8] = pa0_0;
    *(uint4*)&Bl[0][c0i*8] = pb0_0;
    *(uint4*)&Al[0][c1i*8] = pa1_0;
    *(uint4*)&Bl[0][c1i*8] = pb1_0;

    for (int kt = 0; kt < nkt; kt += 2) {
        __syncthreads();
        {
            s16x8 af[4], bfr[4];
            #pragma unroll
            for (int mt=0; mt<4; ++mt) af[mt]  = *(const s16x8*)&Al[0][(((wm>>4)+mt)*64 + lane)*8];
            #pragma unroll
            for (int nt=0; nt<4; ++nt) bfr[nt] = *(const s16x8*)&Bl[0][(((wn>>4)+nt)*64 + lane)*8];
            *(uint4*)&Al[1][c0i*8] = pa0_1;
            *(uint4*)&Bl[1][c0i*8] = pb0_1;
            *(uint4*)&Al[1][c1i*8] = pa1_1;
            *(uint4*)&Bl[1][c1i*8] = pb1_1;
            if (kt+2 < nkt) {
                pa0_0 = *(const uint4*)(gA0 + (kt+2)*32);
                pb0_0 = *(const uint4*)(gB0 + (kt+2)*32);
                pa1_0 = *(const uint4*)(gA1 + (kt+2)*32);
                pb1_0 = *(const uint4*)(gB1 + (kt+2)*32);
            }
            #pragma unroll
            for (int mt=0; mt<4; ++mt)
                #pragma unroll
                for (int nt=0; nt<4; ++nt)
                    acc[mt][nt] = __builtin_amdgcn_mfma_f32_16x16x32_bf16(af[mt], bfr[nt], acc[mt][nt], 0,0,0);
        }
        __syncthreads();
        {
            s16x8 af[4], bfr[4];
            #pragma unroll
            for (int mt=0; mt<4; ++mt) af[mt]  = *(const s16x8*)&Al[1][(((wm>>4)+mt)*64 + lane)*8];
            #pragma unroll
            for (int nt=0; nt<4; ++nt) bfr[nt] = *(const s16x8*)&Bl[1][(((wn>>4)+nt)*64 + lane)*8];
            if (kt+2 < nkt) {
                *(uint4*)&Al[0][c0i*8] = pa0_0;
                *(uint4*)&Bl[0][c0i*8] = pb0_0;
                *(uint4*)&Al[0][c1i*8] = pa1_0;
                *(uint4*)&Bl[0][c1i*8] = pb1_0;
            }
            if (kt+3 < nkt) {
                pa0_1 = *(const uint4*)(gA0 + (kt+3)*32);
                pb0_1 = *(const uint4*)(gB0 + (kt+3)*32);
                pa1_1 = *(const uint4*)(gA1 + (kt+3)*32);
                pb1_1 = *(const uint4*)(gB1 + (kt+3)*32);
            }
            #pragma unroll
            for (int mt=0; mt<4; ++mt)
                #pragma unroll
                for (int nt=0; nt<4; ++nt)
                    acc[mt][nt] = __builtin_amdgcn_mfma_f32_16x16x32_bf16(af[mt], bfr[nt], acc[mt][nt], 0,0,0);
        }
    }

    if (EPI == 0) {
        // fused rope-reduce epilogue (no V store); linear in V -> split-K safe
        const bool kz0 = (blockIdx.z == 0);
        float cs0=0.f, cs1=0.f, cs2=0.f, cs3=0.f;
        #pragma unroll
        for (int mt=0; mt<4; ++mt) {
            #pragma unroll
            for (int r=0; r<4; ++r) {
                int row = m0 + wm + mt*16 + q*4 + r;
                int ii = (row & 1023) << 6;
                #pragma unroll
                for (int nt=0; nt<4; ++nt) {
                    int col = n0 + wn + nt*16 + r0;
                    float vb = acc[mt][nt][r] + (kz0 ? bias[col] : 0.f);
                    float vn = __shfl_xor(vb, 1, 64);
                    float c = w1tp[ii + (col & 63)]*vb + w2tp[ii + (col & 63)]*vn;
                    if (nt == 0) cs0 += c; else if (nt == 1) cs1 += c;
                    else if (nt == 2) cs2 += c; else cs3 += c;
                }
            }
        }
        cs0 += __shfl_xor(cs0, 16, 64); cs0 += __shfl_xor(cs0, 32, 64);
        cs1 += __shfl_xor(cs1, 16, 64); cs1 += __shfl_xor(cs1, 32, 64);
        cs2 += __shfl_xor(cs2, 16, 64); cs2 += __shfl_xor(cs2, 32, 64);
        cs3 += __shfl_xor(cs3, 16, 64); cs3 += __shfl_xor(cs3, 32, 64);
        if (lane < 16) {
            int b = m0 >> 10;
            atomicAdd(&vsump[b*1536 + n0 + wn +  0 + lane], cs0);
            atomicAdd(&vsump[b*1536 + n0 + wn + 16 + lane], cs1);
            atomicAdd(&vsump[b*1536 + n0 + wn + 32 + lane], cs2);
            atomicAdd(&vsump[b*1536 + n0 + wn + 48 + lane], cs3);
        }
    } else {
        float* pd = (EPI == 6) ? (blockIdx.z ? o32b : o32) : nullptr;
        #pragma unroll
        for (int mt=0; mt<4; ++mt) {
            #pragma unroll
            for (int nt=0; nt<4; ++nt) {
                int col = n0 + wn + nt*16 + r0;
                #pragma unroll
                for (int r=0; r<4; ++r) {
                    int row = m0 + wm + mt*16 + q*4 + r;
                    float v = acc[mt][nt][r];
                    if (EPI == 6) {
                        pd[(size_t)row*768 + col] = v;
                    } else {
                        o16[(size_t)row*2304 + 768 + col] = f2b(v);
                    }
                }
            }
        }
    }
}

// ---- combine: out = p0 + p1 + cvecb[b] + x  (float4, 3072 blocks) ----
__global__ __launch_bounds__(256) void combine_out(const float* __restrict__ p0,
    const float* __restrict__ p1, const float* __restrict__ cvecb,
    const float* __restrict__ x, float* __restrict__ out)
{
    size_t i = ((size_t)blockIdx.x*256 + threadIdx.x)*4;
    int col = (int)(i % 768);
    int b   = (int)((i / 768) >> 10);
    float4 a  = *(const float4*)(p0 + i);
    float4 bq = *(const float4*)(p1 + i);
    float4 xx = *(const float4*)(x + i);
    const float* cv = cvecb + b*768 + col;
    float4 r;
    r.x = a.x + bq.x + xx.x + cv[0];
    r.y = a.y + bq.y + xx.y + cv[1];
    r.z = a.z + bq.z + xx.z + cv[2];
    r.w = a.w + bq.w + xx.w + cv[3];
    *(float4*)(out + i) = r;
}

// ============ mega_prep: all input-independent prep in ONE launch (R7) ============
// Segments (13574 blocks total):
//   [0,1152) Wqkv packs  [1152,3456) W1 pack  [3456,4032) fold1  [4032,4608) pack_bts
//   [4608,9216) cast W2  [9216,9222) pack_bv  [9222,9478) tables/inits  [9478,13574) ln_x
__global__ __launch_bounds__(256) void mega_prep(
    const float* __restrict__ Wqkv, const float* __restrict__ W1,
    const float* __restrict__ Wout, const float* __restrict__ W2,
    const float* __restrict__ ls2,  const float* __restrict__ bqkv,
    const float* __restrict__ x,
    const float* __restrict__ g1, const float* __restrict__ b1v,
    const float* __restrict__ g2, const float* __restrict__ b2v,
    const float* __restrict__ R,  const float* __restrict__ rng,
    const float* __restrict__ rnb, const float* __restrict__ bproj,
    const float* __restrict__ bout,
    ushort* __restrict__ WvT, ushort* __restrict__ W1T, ushort* __restrict__ BTf,
    ushort* __restrict__ Afold, ushort* __restrict__ BT2, float* __restrict__ bvp,
    float* __restrict__ w1t, float* __restrict__ w2t, float* __restrict__ wvec,
    float* __restrict__ attn_c, float* __restrict__ vsum, float* __restrict__ cvecb,
    ushort* __restrict__ xa, ushort* __restrict__ xm, ushort* __restrict__ xc)
{
    __shared__ float tl[32*33];
    const int blk = blockIdx.x;
    const int t = threadIdx.x;

    if (blk < 1152) {
        int p = blk / 576, l = blk % 576;
        int kt = (l % 24)*32, nt = (l / 24)*32;
        const float* src = Wqkv + (size_t)p*768*2304;
        ushort* dst = WvT + (size_t)p*768*768;
        int nl = t & 31, kg = t >> 5;
        #pragma unroll
        for (int kk=0; kk<4; ++kk) {
            int k = kg*4 + kk;
            tl[k*33 + nl] = src[(size_t)(kt + k)*2304 + 1536 + nt + nl];
        }
        __syncthreads();
        int kcol = t & 31, ng = t >> 5;
        #pragma unroll
        for (int nn=0; nn<4; ++nn) {
            int nrow = ng*4 + nn;
            dst[(size_t)(nt + nrow)*768 + kt + kcol] = f2b(tl[kcol*33 + nrow]);
        }
    } else if (blk < 3456) {
        int l = blk - 1152;
        int kt = (l % 24)*32, nt = (l / 24)*32;
        int nl = t & 31, kg = t >> 5;
        #pragma unroll
        for (int kk=0; kk<4; ++kk) {
            int k = kg*4 + kk;
            tl[k*33 + nl] = W1[(size_t)(kt + k)*3072 + nt + nl];
        }
        __syncthreads();
        int kcol = t & 31, ng = t >> 5;
        #pragma unroll
        for (int nn=0; nn<4; ++nn) {
            int nrow = ng*4 + nn;
            W1T[(size_t)(nt + nrow)*768 + kt + kcol] = f2b(tl[kcol*33 + nrow]);
        }
    } else if (blk < 4032) {
        int l = blk - 3456;
        int kt = (l % 24)*32, nt = (l / 24)*32;
        int nl = t & 31, kg = t >> 5;
        #pragma unroll
        for (int kk=0; kk<4; ++kk) {
            int k = kg*4 + kk;
            tl[k*33 + nl] = Wout[(size_t)(kt + k)*768 + nt + nl]
                          + Wout[(size_t)(768 + kt + k)*768 + nt + nl];
        }
        __syncthreads();
        int kcol = t & 31, ng = t >> 5;
        #pragma unroll
        for (int nn=0; nn<4; ++nn) {
            int nrow = ng*4 + nn;
            BTf[(size_t)(nt + nrow)*2304 + kt + kcol] = f2b(tl[kcol*33 + nrow]);
        }
    } else if (blk < 4608) {
        int l = blk - 4032;
        int kt = (l % 24)*32, nt = (l / 24)*32;
        const float* src = Wout + (size_t)768*768;
        int nl = t & 31, kg = t >> 5;
        #pragma unroll
        for (int kk=0; kk<4; ++kk) {
            int k = kg*4 + kk;
            tl[k*33 + nl] = src[(size_t)(kt + k)*768 + nt + nl];
        }
        __syncthreads();
        int kcol = t & 31, ng = t >> 5;
        #pragma unroll
        for (int nn=0; nn<4; ++nn) {
            int nrow = ng*4 + nn;
            Afold[(size_t)(nt + nrow)*768 + kt + kcol] = f2b(tl[kcol*33 + nrow] * ls2[kt + kcol]);
        }
    } else if (blk < 9216) {
        int i = (blk - 4608)*256 + t;
        BT2[i] = f2b(W2[i]);
    } else if (blk < 9222) {
        int i = (blk - 9216)*256 + t;
        if (i < 1536) bvp[i] = bqkv[(i/768)*2304 + 1536 + (i%768)];
    } else if (blk < 9478) {
        int pb = blk - 9222;
        int idx = pb*256 + t;
        {
            int i = idx >> 6, j = idx & 63;
            float w1, w2;
            if (j < 32) {
                int m = j >> 1;
                float inv = powf(10000.f, -(float)m*(1.f/16.f));
                float fr = (float)i * inv;
                float c = cosf(fr), sn = sinf(fr);
                float power = ((float)i - 512.f) * (1.f/512.f);
                float basev = (2.f*(float)(j & 15) + 12.8f) * (1.f/44.8f);
                float sfac = powf(basev, -power);
                w1 = c * sfac;
                w2 = ((j & 1) ? sn : -sn) * sfac;
            } else { w1 = 1.f; w2 = 0.f; }
            w1t[idx] = w1; w2t[idx] = w2;
        }
        if (pb >= 1 && pb <= 12) {
            int k = (pb-1)*256 + t;
            int o = k % 768;
            attn_c[k] = bproj[o] + bproj[768 + o];
        }
        if (pb >= 13 && pb <= 36) {
            int k = (pb-13)*256 + t;
            vsum[k] = 0.f;
        }
        if (pb >= 37 && pb <= 48) {
            int k = (pb-37)*256 + t;
            cvecb[k] = bout[k % 768];
        }
        if (pb == 0) {
            float* mixs = tl;
            float* wsb  = tl + 32;
            if (t < 24) {
                int p = t / 12, g = t % 12;
                float m = 0.f;
                for (int h=0; h<12; ++h) m += R[p*144 + h*12 + g];
                mixs[t] = m;
            }
            __syncthreads();
            if (t < 2) {
                float mean=0.f, var=0.f;
                for (int g=0; g<12; ++g) mean += mixs[t*12+g];
                mean *= (1.f/12.f);
                for (int g=0; g<12; ++g){ float d = mixs[t*12+g]-mean; var += d*d; }
                var *= (1.f/12.f);
                float rstd = rsqrtf(var + 1e-5f);
                for (int g=0; g<12; ++g)
                    wsb[t*12+g] = (mixs[t*12+g]-mean)*rstd*rng[t*12+g] + rnb[t*12+g];
            }
            __syncthreads();
            if (t < 24) wvec[t] = wsb[t];
        }
    } else {
        int row = blk - 9478;
        float* sb = tl;
        float v[3]; float s = 0.f, ss = 0.f;
        #pragma unroll
        for (int e=0; e<3; ++e) { v[e] = x[(size_t)row*768 + t + e*256]; s += v[e]; ss += v[e]*v[e]; }
        for (int o=32; o>0; o>>=1){ s += __shfl_down(s,o,64); ss += __shfl_down(ss,o,64); }
        int lane = t&63, w = t>>6;
        if (lane==0){ sb[w]=s; sb[4+w]=ss; }
        __syncthreads();
        s = sb[0]+sb[1]+sb[2]+sb[3]; ss = sb[4]+sb[5]+sb[6]+sb[7];
        float mean = s*(1.f/768.f);
        float var  = ss*(1.f/768.f) - mean*mean;
        float rstd = rsqrtf(var + 1e-5f);
        #pragma unroll
        for (int e=0; e<3; ++e){
            int c = t + e*256;
            float n = (v[e]-mean)*rstd;
            xa[(size_t)row*768 + c] = f2b(n*g1[c] + b1v[c]);
            xm[(size_t)row*768 + c] = f2b(n*g2[c] + b2v[c]);
            xc[(size_t)row*2304 + c] = f2b(v[e]);
        }
    }
}

// ------- attn_c[b][o] += sum_c (wvec*vsum)[b][c] * Wproj[p][c][o]  (R9: 48-chunks, 384 blocks) -------
__global__ __launch_bounds__(256) void attn_gemm(const float* __restrict__ vsum,
    const float* __restrict__ wvec, const float* __restrict__ Wproj, float* __restrict__ attn_c)
{
    int o  = blockIdx.x*256 + threadIdx.x;
    int c0 = blockIdx.y * 48;
    int b  = blockIdx.z;
    int p  = c0 / 768;
    float acc = 0.f;
    #pragma unroll 4
    for (int cc=0; cc<48; ++cc) {
        int c = c0 + cc;
        int cl = c - p*768;
        float y = wvec[p*12 + (cl>>6)] * vsum[b*1536 + c];
        acc += y * Wproj[(size_t)p*589824 + (size_t)cl*768 + o];
    }
    atomicAdd(&attn_c[b*768 + o], acc);
}

// ---- cvecb[b,o] += chunked reduction over 1536 Wout rows (R9: 48-chunks, 384 blocks) ----
__global__ __launch_bounds__(256) void cvec_kernel(const float* __restrict__ attn_c,
    const float* __restrict__ ls1, const float* __restrict__ ls2, const float* __restrict__ b2,
    const float* __restrict__ Wout, float* __restrict__ cvecb)
{
    int o  = blockIdx.x*256 + threadIdx.x;
    int r0 = blockIdx.y * 48;
    int b  = blockIdx.z;
    float acc = 0.f;
    #pragma unroll 4
    for (int rr = 0; rr < 48; ++rr) {
        int r = r0 + rr;
        float coef = (r < 768) ? ls1[r]*attn_c[b*768 + r]
                               : ls2[r-768]*b2[r-768];
        acc += coef * Wout[(size_t)r*768 + o];
    }
    atomicAdd(&cvecb[b*768 + o], acc);
}

// ---------------- gate LN stats only: mean/rstd per row -> stats[row] ----------------
__global__ __launch_bounds__(256) void ln_stats(const ushort* __restrict__ xg,
    float2* __restrict__ stats)
{
    __shared__ float sb[8];
    int row = blockIdx.x, t = threadIdx.x;
    float s=0.f, ss=0.f;
    #pragma unroll
    for (int e=0;e<6;++e){ float v = b2f(xg[(size_t)row*1536 + t + e*256]); s+=v; ss+=v*v; }
    for (int o=32; o>0; o>>=1){ s += __shfl_down(s,o,64); ss += __shfl_down(ss,o,64); }
    int lane = t&63, w = t>>6;
    if (lane==0){ sb[w]=s; sb[4+w]=ss; }
    __syncthreads();
    s = sb[0]+sb[1]+sb[2]+sb[3]; ss = sb[4]+sb[5]+sb[6]+sb[7];
    float mean = s*(1.f/1536.f);
    float var  = ss*(1.f/1536.f) - mean*mean;
    if (t == 0) stats[row] = make_float2(mean, rsqrtf(var + 1e-5f));
}

// ------- depthwise conv (K=21) + xr multiply; LN applied inline during staging -------
#define CROWS 128
#define CIN   (CROWS + 20)
#define CSTR  72
__global__ __launch_bounds__(256) void conv_mul(const ushort* __restrict__ xg,
    const float2* __restrict__ stats,
    const float* __restrict__ gg, const float* __restrict__ gb,
    const float* __restrict__ cw, const float* __restrict__ cb,
    const ushort* __restrict__ xr, ushort* __restrict__ u)
{
    __shared__ ushort tile[CIN * CSTR];
    const int c0 = blockIdx.x * 64;
    const int i0 = blockIdx.y * CROWS;
    const int b  = blockIdx.z;
    const int t  = threadIdx.x;
    const size_t base = (size_t)b*1024*1536;

    #pragma unroll
    for (int it = 0; it < 5; ++it) {
        int idx = it*256 + t;
        if (idx < CIN*8) {
            int r  = idx >> 3;
            int cq = (idx & 7) * 8;
            int si = i0 + r - 10;
            uint4 val = make_uint4(0u,0u,0u,0u);
            if (si >= 0 && si < 1024) {
                uint4 raw = *(const uint4*)(xg + base + (size_t)si*1536 + c0 + cq);
                float2 st = stats[b*1024 + si];
                const ushort* rp = (const ushort*)&raw;
                ushort* vp = (ushort*)&val;
                #pragma unroll
                for (int e=0; e<8; ++e) {
                    int c = c0 + cq + e;
                    vp[e] = f2b((b2f(rp[e]) - st.x)*st.y*gg[c] + gb[c]);
                }
            }
            *(uint4*)&tile[r*CSTR + cq] = val;
        }
    }
    __syncthreads();

    const int ch = t & 63;
    const int o0 = (t >> 6) * 32;
    const int c  = c0 + ch;

    float w[21];
    #pragma unroll
    for (int k=0; k<21; ++k) w[k] = cw[c*21 + k];
    const float bias = cb[c];

    float win[21];
    #pragma unroll
    for (int j=0; j<20; ++j) win[j] = b2f(tile[(o0+j)*CSTR + ch]);

    #pragma unroll
    for (int j=0; j<32; ++j) {
        win[(j+20)%21] = b2f(tile[(o0+j+20)*CSTR + ch]);
        float acc = bias;
        #pragma unroll
        for (int k=0; k<21; ++k) acc += win[(j+k)%21] * w[k];
        size_t offr = base + (size_t)(i0+o0+j)*1536 + c;
        u[(size_t)(b*1024 + i0+o0+j)*2304 + 768 + c] = f2b(b2f(xr[offr]) * acc);
    }
}

extern "C" void kernel_launch(void* const* d_in, const int* in_sizes, int n_in,
                              void* d_out, int out_size, void* d_ws, size_t ws_size,
                              hipStream_t stream)
{
    const float* x     = (const float*)d_in[0];
    const float* Wqkv  = (const float*)d_in[1];
    const float* bqkv  = (const float*)d_in[2];
    const float* Wproj = (const float*)d_in[3];
    const float* bproj = (const float*)d_in[4];
    const float* Rw    = (const float*)d_in[9];
    const float* rng   = (const float*)d_in[10];
    const float* rnb   = (const float*)d_in[11];
    const float* ln1g  = (const float*)d_in[12];
    const float* ln1b  = (const float*)d_in[13];
    const float* ln2g  = (const float*)d_in[14];
    const float* ln2b  = (const float*)d_in[15];
    const float* ls1   = (const float*)d_in[16];
    const float* ls2   = (const float*)d_in[17];
    const float* W1    = (const float*)d_in[18];
    const float* b1    = (const float*)d_in[19];
    const float* gng   = (const float*)d_in[20];
    const float* gnb   = (const float*)d_in[21];
    const float* cw    = (const float*)d_in[22];
    const float* cb    = (const float*)d_in[23];
    const float* W2    = (const float*)d_in[24];
    const float* b2    = (const float*)d_in[25];
    const float* Wout  = (const float*)d_in[26];
    const float* bout  = (const float*)d_in[27];
    float* out = (float*)d_out;

    char* ws = (char*)d_ws;
    size_t off = 0;
    auto alloc = [&](size_t bytes)->char* {
        char* p = ws + off;
        off += (bytes + 255) & ~(size_t)255;
        return p;
    };
    ushort* WvT   = (ushort*)alloc(1536*768*2);    // [pc][k]
    ushort* W1T   = (ushort*)alloc(3072*768*2);
    ushort* BT2   = (ushort*)alloc(1536*768*2);    // bf16(W2), [c][d]
    ushort* Afold = (ushort*)alloc(768*768*2);     // ls2[d]*Wout_bot^T, [n][d]
    ushort* BTf   = (ushort*)alloc(768*2304*2);    // folded B^T for final GEMM
    float*  bvp   = (float*)alloc(1536*4);
    float*  w1t   = (float*)alloc(65536*4);
    float*  w2t   = (float*)alloc(65536*4);
    float*  wvec  = (float*)alloc(24*4);
    float*  attnc = (float*)alloc(3072*4);
    float*  vsum  = (float*)alloc(6144*4);
    float*  cvecb = (float*)alloc(3072*4);
    float2* stats = (float2*)alloc(4096*8);
    ushort* xa16  = (ushort*)alloc(4096*768*2);
    ushort* xm16  = (ushort*)alloc(4096*768*2);    // xa16+xm16 contiguous -> p0 alias (12.6MB f32)
    ushort* xr16  = (ushort*)alloc(4096*1536*2);   // GEMM1 left-half output
    ushort* xg16  = (ushort*)alloc(4096*1536*2);   // GEMM1 right-half output -> p1 alias
    ushort* xcat  = (ushort*)alloc((size_t)4096*2304*2);  // [bf16(x) | u]
    float* p0 = (float*)xa16;   // dead after V-proj + GEMM1 (both precede final GEMM)
    float* p1 = (float*)xg16;   // dead after conv_mul (precedes final GEMM)
    (void)ws_size; (void)n_in; (void)in_sizes; (void)out_size;

    (void)hipFuncSetAttribute((const void*)gemm256<1>, hipFuncAttributeMaxDynamicSharedMemorySize, 131072);

    // ---- all input-independent prep in ONE launch ----
    mega_prep<<<dim3(13574), 256, 0, stream>>>(
        Wqkv, W1, Wout, W2, ls2, bqkv, x,
        ln1g, ln1b, ln2g, ln2b, Rw, rng, rnb, bproj, bout,
        WvT, W1T, BTf, Afold, BT2, bvp,
        w1t, w2t, wvec, attnc, vsum, cvecb,
        xa16, xm16, xcat);

    // ---- Wfold2: BTf right half = (ls2*Wout_bot)^T @ W2^T ----
    gemm_bf16<4><<<dim3(12, 6), 256, 0, stream>>>(Afold, BT2, 768, 1536, 768, 768, 768,
                                                  nullptr, nullptr, nullptr, nullptr,
                                                  BTf, nullptr, nullptr);

    // ---- V projection with FUSED rope-reduce, split-K=2 (rope epilogue linear in V) ----
    gemm_bf16<0><<<dim3(12, 32, 2), 256, 0, stream>>>(xa16, WvT, 4096, 1536, 384, 768, 768,
                                                      bvp, w1t, w2t, vsum,
                                                      nullptr, nullptr, nullptr);
    // ---- reattn projection to per-batch constant ----
    attn_gemm<<<dim3(3, 32, 4), 256, 0, stream>>>(vsum, wvec, Wproj, attnc);
    // ---- per-batch output constant ----
    cvec_kernel<<<dim3(3, 32, 4), 256, 0, stream>>>(attnc, ls1, ls2, b2, Wout, cvecb);

    // ---- MLP ----
    gemm256<1><<<dim3(12, 16), 512, 131072, stream>>>(xm16, W1T, 4096, 3072, 768,
                                                      b1, xr16, xg16);
    ln_stats<<<dim3(4096), 256, 0, stream>>>(xg16, stats);
    conv_mul<<<dim3(24, 8, 4), 256, 0, stream>>>(xg16, stats, gng, gnb, cw, cb, xr16, xcat);

    // ---- final projection, split-K=2: partials (f32) into recycled buffers ----
    gemm_bf16<6><<<dim3(6, 32, 2), 256, 0, stream>>>(xcat, BTf, 4096, 768, 1152, 2304, 2304,
                                                     nullptr, nullptr, nullptr, nullptr,
                                                     nullptr, p0, p1);
    // ---- out = p0 + p1 + cvecb[b] + x ----
    combine_out<<<dim3(3072), 256, 0, stream>>>(p0, p1, cvecb, x, out);
}

// Round 10
// 311.333 us; speedup vs baseline: 1.3997x; 1.3997x over previous
//
#include <hip/hip_runtime.h>
#include <hip/hip_bf16.h>

typedef short s16x8 __attribute__((ext_vector_type(8)));
typedef float f32x4 __attribute__((ext_vector_type(4)));

#define C2 1536

__device__ __forceinline__ float b2f(ushort u){ return __uint_as_float(((unsigned)u)<<16); }
__device__ __forceinline__ ushort f2b(float f){ unsigned u = __float_as_uint(f); return (ushort)((u + 0x7fffu + ((u>>16)&1u)) >> 16); }

// async global -> LDS, 16B per lane at wave-uniform LDS base + lane*16
#define GL16(g, l) __builtin_amdgcn_global_load_lds( \
    (const __attribute__((address_space(1))) void*)(g), \
    (__attribute__((address_space(3))) void*)(l), 16, 0, 0)

#define VMW(n) asm volatile("s_waitcnt vmcnt(" #n ")" ::: "memory")
#define LGW()  asm volatile("s_waitcnt lgkmcnt(0)" ::: "memory")
#define SB()   __builtin_amdgcn_sched_barrier(0)
#define BAR()  __builtin_amdgcn_s_barrier()
#define SP1    __builtin_amdgcn_s_setprio(1)
#define SP0    __builtin_amdgcn_s_setprio(0)
#define MF(va, vb, c) __builtin_amdgcn_mfma_f32_16x16x32_bf16(va, vb, c, 0,0,0)

// ======================= 256x256 8-phase bf16 GEMM (verified R3-R8) =======================
// Used only for MLP GEMM1 (M=4096,N=3072,K=768; 192 blocks). See R3 notes.
#define RDA(P, mh) { const int ab = (P) + aro + (mh)*4096; \
    a0=L8(ab+sx0);      a1=L8(ab+sx1); \
    a2=L8(ab+1024+sx0); a3=L8(ab+1024+sx1); \
    a4=L8(ab+2048+sx0); a5=L8(ab+2048+sx1); \
    a6=L8(ab+3072+sx0); a7=L8(ab+3072+sx1); }
#define RDB0(P, nh) { const int bb = (P) + bro + (nh)*2048; \
    b00=L8(bb+sx0); b01=L8(bb+sx1); b02=L8(bb+1024+sx0); b03=L8(bb+1024+sx1); }
#define RDB1(P, nh) { const int bb = (P) + bro + (nh)*2048; \
    b10=L8(bb+sx0); b11=L8(bb+sx1); b12=L8(bb+1024+sx0); b13=L8(bb+1024+sx1); }
#define L8(off) (*(const s16x8*)&lds[off])
#define STG(p0, p1, T, dstb) { \
    GL16((p0) + (size_t)(T)*64, &lds[(dstb) + ldsw]); \
    GL16((p1) + (size_t)(T)*64, &lds[(dstb) + 4096 + ldsw]); }
#define QD(mh, nh, B0,B1,B2,B3) { \
  acc[(mh)*4+0][(nh)*2+0]=MF(a0,B0,acc[(mh)*4+0][(nh)*2+0]); \
  acc[(mh)*4+0][(nh)*2+0]=MF(a1,B1,acc[(mh)*4+0][(nh)*2+0]); \
  acc[(mh)*4+0][(nh)*2+1]=MF(a0,B2,acc[(mh)*4+0][(nh)*2+1]); \
  acc[(mh)*4+0][(nh)*2+1]=MF(a1,B3,acc[(mh)*4+0][(nh)*2+1]); \
  acc[(mh)*4+1][(nh)*2+0]=MF(a2,B0,acc[(mh)*4+1][(nh)*2+0]); \
  acc[(mh)*4+1][(nh)*2+0]=MF(a3,B1,acc[(mh)*4+1][(nh)*2+0]); \
  acc[(mh)*4+1][(nh)*2+1]=MF(a2,B2,acc[(mh)*4+1][(nh)*2+1]); \
  acc[(mh)*4+1][(nh)*2+1]=MF(a3,B3,acc[(mh)*4+1][(nh)*2+1]); \
  acc[(mh)*4+2][(nh)*2+0]=MF(a4,B0,acc[(mh)*4+2][(nh)*2+0]); \
  acc[(mh)*4+2][(nh)*2+0]=MF(a5,B1,acc[(mh)*4+2][(nh)*2+0]); \
  acc[(mh)*4+2][(nh)*2+1]=MF(a4,B2,acc[(mh)*4+2][(nh)*2+1]); \
  acc[(mh)*4+2][(nh)*2+1]=MF(a5,B3,acc[(mh)*4+2][(nh)*2+1]); \
  acc[(mh)*4+3][(nh)*2+0]=MF(a6,B0,acc[(mh)*4+3][(nh)*2+0]); \
  acc[(mh)*4+3][(nh)*2+0]=MF(a7,B1,acc[(mh)*4+3][(nh)*2+0]); \
  acc[(mh)*4+3][(nh)*2+1]=MF(a6,B2,acc[(mh)*4+3][(nh)*2+1]); \
  acc[(mh)*4+3][(nh)*2+1]=MF(a7,B3,acc[(mh)*4+3][(nh)*2+1]); }

#define EIGHT(t0, t1, DS, VM4) \
  /*P0*/ VMW(4); BAR(); \
  RDA(0,0); RDB0(0,0); \
  STG(pA00,pA01,(t1), 16384); \
  LGW(); SB(); SP1; QD(0,0,b00,b01,b02,b03); SP0; BAR(); \
  /*P1*/ RDB1(0,1); \
  STG(pA10,pA11,(t1), 24576); \
  BAR(); LGW(); SB(); SP1; QD(0,1,b10,b11,b12,b13); SP0; BAR(); \
  /*P2*/ RDA(0,1); \
  if (DS) { STG(pB00,pB01,(t0)+2, 32768); } \
  BAR(); LGW(); SB(); SP1; QD(1,0,b00,b01,b02,b03); SP0; BAR(); \
  /*P3*/ if (DS) { STG(pB10,pB11,(t0)+2, 40960); } \
  BAR(); SP1; QD(1,1,b10,b11,b12,b13); SP0; BAR(); \
  /*P4*/ VM4; BAR(); \
  RDA(16384,0); RDB0(16384,0); \
  if (DS) { STG(pA00,pA01,(t0)+2, 0); } \
  LGW(); SB(); SP1; QD(0,0,b00,b01,b02,b03); SP0; BAR(); \
  /*P5*/ RDB1(16384,1); \
  if (DS) { STG(pA10,pA11,(t0)+2, 8192); } \
  BAR(); LGW(); SB(); SP1; QD(0,1,b10,b11,b12,b13); SP0; BAR(); \
  /*P6*/ RDA(16384,1); \
  if (DS) { STG(pB00,pB01,(t1)+2, 49152); } \
  BAR(); LGW(); SB(); SP1; QD(1,0,b00,b01,b02,b03); SP0; BAR(); \
  /*P7*/ if (DS) { STG(pB10,pB11,(t1)+2, 57344); } \
  BAR(); SP1; QD(1,1,b10,b11,b12,b13); SP0; BAR();

template<int EPI>
__global__ __launch_bounds__(512, 1) void gemm256(
    const ushort* __restrict__ A, const ushort* __restrict__ BT,
    int M, int N, int K,
    const float* __restrict__ bias,
    ushort* __restrict__ o16, ushort* __restrict__ o16b)
{
    extern __shared__ ushort lds[];
    const int t = threadIdx.x;
    const int lane = t & 63, wv = t >> 6;
    const int wr = wv >> 2, wc = wv & 3;
    const int r0 = lane & 15, q = lane >> 4, e7 = lane & 7;
    const int m0 = blockIdx.y*256, n0 = blockIdx.x*256;

    const int idx = wv*64 + lane;
    const int lr8 = idx >> 3;
    const int ksrc = (idx & 7) ^ (lr8 & 7);
    const ushort* pA00 = A  + (size_t)(m0 +   0 +  0 + lr8)*K + ksrc*8;
    const ushort* pA01 = A  + (size_t)(m0 +   0 + 64 + lr8)*K + ksrc*8;
    const ushort* pA10 = A  + (size_t)(m0 + 128 +  0 + lr8)*K + ksrc*8;
    const ushort* pA11 = A  + (size_t)(m0 + 128 + 64 + lr8)*K + ksrc*8;
    const ushort* pB00 = BT + (size_t)(n0 +   0 +  0 + lr8)*K + ksrc*8;
    const ushort* pB01 = BT + (size_t)(n0 +   0 + 64 + lr8)*K + ksrc*8;
    const ushort* pB10 = BT + (size_t)(n0 + 128 +  0 + lr8)*K + ksrc*8;
    const ushort* pB11 = BT + (size_t)(n0 + 128 + 64 + lr8)*K + ksrc*8;
    const int ldsw = wv*512;

    const int aro = (wr*128 + r0)*64;
    const int bro = 32768 + (wc*64 + r0)*64;
    const int sx0 = (q ^ e7)*8, sx1 = ((q ^ e7)*8) ^ 32;

    f32x4 acc[8][4];
    #pragma unroll
    for (int i=0;i<8;++i)
        #pragma unroll
        for (int j=0;j<4;++j) acc[i][j] = (f32x4){0.f,0.f,0.f,0.f};
    s16x8 a0,a1,a2,a3,a4,a5,a6,a7;
    s16x8 b00,b01,b02,b03, b10,b11,b12,b13;

    const int nkt = K >> 6;
    const int niter = nkt >> 1;

    STG(pB00,pB01, 0, 32768);
    STG(pB10,pB11, 0, 40960);
    STG(pA00,pA01, 0, 0);
    STG(pA10,pA11, 0, 8192);
    STG(pB00,pB01, 1, 49152);
    STG(pB10,pB11, 1, 57344);

    for (int i = 0; i < niter-1; ++i) {
        const int t0 = 2*i, t1 = 2*i+1;
        EIGHT(t0, t1, 1, VMW(4));
    }
    {
        const int t0 = nkt-2, t1 = nkt-1;
        EIGHT(t0, t1, 0, VMW(0));
    }

    #pragma unroll
    for (int gm=0; gm<8; ++gm) {
        #pragma unroll
        for (int gn=0; gn<4; ++gn) {
            int col = n0 + wc*64 + gn*16 + r0;
            #pragma unroll
            for (int r=0; r<4; ++r) {
                int row = m0 + wr*128 + gm*16 + q*4 + r;
                float v = acc[gm][gn][r];
                if (EPI == 0) {
                    o16[(size_t)row*N + col] = f2b(v + bias[col]);
                } else {
                    v += bias[col];
                    float g = 0.5f*v*(1.0f + erff(v*0.70710678118f));
                    if (col < C2) o16 [(size_t)row*C2 + col]        = f2b(g);
                    else          o16b[(size_t)row*C2 + (col - C2)] = f2b(g);
                }
            }
        }
    }
}

// ---------------- 128x128 bf16 MFMA GEMM (R0 reg-staged, distance-2 prefetch) ----------------
// EPI 0: V-projection with FUSED rope-reduce (R8, no split-K — R9's split-K reverted:
//        unattributable under throttled-pod measurement, and adds partial-traffic).
// EPI 3: out[row*768+col] = acc + cvecb[(row>>10)*768+col] + x[row*768+col]  (final, fused fold)
// EPI 4: o16[row*2304 + 768 + col] = bf16(acc)                               (Wfold2 -> BTf right)
template<int EPI>
__global__ __launch_bounds__(256) void gemm_bf16(
    const ushort* __restrict__ A, const ushort* __restrict__ BT,
    int M, int N, int K, int lda, int ldbt,
    const float* __restrict__ bias, const float* __restrict__ xres,
    const float* __restrict__ w1tp, const float* __restrict__ w2tp, float* __restrict__ vsump,
    ushort* __restrict__ o16, float* __restrict__ o32)
{
    __shared__ ushort Al[2][128*32];
    __shared__ ushort Bl[2][128*32];
    const int t = threadIdx.x;
    const int m0 = blockIdx.y*128, n0 = blockIdx.x*128;
    const int lane = t & 63, wv = t >> 6;
    const int wm = (wv>>1)*64, wn = (wv&1)*64;
    const int r0 = lane & 15, q = lane >> 4;

    const int c0i = t, c1i = t + 256;
    const int lrow0 = ((c0i>>6)<<4) | (c0i&15), lkc0 = ((c0i>>4)&3) << 3;
    const int lrow1 = ((c1i>>6)<<4) | (c1i&15), lkc1 = ((c1i>>4)&3) << 3;
    const ushort* gA0 = A  + (size_t)(m0+lrow0)*lda + lkc0;
    const ushort* gB0 = BT + (size_t)(n0+lrow0)*ldbt + lkc0;
    const ushort* gA1 = A  + (size_t)(m0+lrow1)*lda + lkc1;
    const ushort* gB1 = BT + (size_t)(n0+lrow1)*ldbt + lkc1;

    f32x4 acc[4][4];
    #pragma unroll
    for (int i=0;i<4;++i)
        #pragma unroll
        for (int j=0;j<4;++j) acc[i][j] = (f32x4){0.f,0.f,0.f,0.f};

    const int nkt = K >> 5;
    uint4 pa0_0, pb0_0, pa1_0, pb1_0;
    uint4 pa0_1, pb0_1, pa1_1, pb1_1;
    pa0_0 = *(const uint4*)gA0;        pb0_0 = *(const uint4*)gB0;
    pa1_0 = *(const uint4*)gA1;        pb1_0 = *(const uint4*)gB1;
    pa0_1 = *(const uint4*)(gA0 + 32); pb0_1 = *(const uint4*)(gB0 + 32);
    pa1_1 = *(const uint4*)(gA1 + 32); pb1_1 = *(const uint4*)(gB1 + 32);
    *(uint4*)&Al[0][c0i*8] = pa0_0;
    *(uint4*)&Bl[0][c0i*8] = pb0_0;
    *(uint4*)&Al[0][c1i*8] = pa1_0;
    *(uint4*)&Bl[0][c1i*8] = pb1_0;

    for (int kt = 0; kt < nkt; kt += 2) {
        __syncthreads();
        {
            s16x8 af[4], bfr[4];
            #pragma unroll
            for (int mt=0; mt<4; ++mt) af[mt]  = *(const s16x8*)&Al[0][(((wm>>4)+mt)*64 + lane)*8];
            #pragma unroll
            for (int nt=0; nt<4; ++nt) bfr[nt] = *(const s16x8*)&Bl[0][(((wn>>4)+nt)*64 + lane)*8];
            *(uint4*)&Al[1][c0i*8] = pa0_1;
            *(uint4*)&Bl[1][c0i*8] = pb0_1;
            *(uint4*)&Al[1][c1i*8] = pa1_1;
            *(uint4*)&Bl[1][c1i*8] = pb1_1;
            if (kt+2 < nkt) {
                pa0_0 = *(const uint4*)(gA0 + (kt+2)*32);
                pb0_0 = *(const uint4*)(gB0 + (kt+2)*32);
                pa1_0 = *(const uint4*)(gA1 + (kt+2)*32);
                pb1_0 = *(const uint4*)(gB1 + (kt+2)*32);
            }
            #pragma unroll
            for (int mt=0; mt<4; ++mt)
                #pragma unroll
                for (int nt=0; nt<4; ++nt)
                    acc[mt][nt] = __builtin_amdgcn_mfma_f32_16x16x32_bf16(af[mt], bfr[nt], acc[mt][nt], 0,0,0);
        }
        __syncthreads();
        {
            s16x8 af[4], bfr[4];
            #pragma unroll
            for (int mt=0; mt<4; ++mt) af[mt]  = *(const s16x8*)&Al[1][(((wm>>4)+mt)*64 + lane)*8];
            #pragma unroll
            for (int nt=0; nt<4; ++nt) bfr[nt] = *(const s16x8*)&Bl[1][(((wn>>4)+nt)*64 + lane)*8];
            if (kt+2 < nkt) {
                *(uint4*)&Al[0][c0i*8] = pa0_0;
                *(uint4*)&Bl[0][c0i*8] = pb0_0;
                *(uint4*)&Al[0][c1i*8] = pa1_0;
                *(uint4*)&Bl[0][c1i*8] = pb1_0;
            }
            if (kt+3 < nkt) {
                pa0_1 = *(const uint4*)(gA0 + (kt+3)*32);
                pb0_1 = *(const uint4*)(gB0 + (kt+3)*32);
                pa1_1 = *(const uint4*)(gA1 + (kt+3)*32);
                pb1_1 = *(const uint4*)(gB1 + (kt+3)*32);
            }
            #pragma unroll
            for (int mt=0; mt<4; ++mt)
                #pragma unroll
                for (int nt=0; nt<4; ++nt)
                    acc[mt][nt] = __builtin_amdgcn_mfma_f32_16x16x32_bf16(af[mt], bfr[nt], acc[mt][nt], 0,0,0);
        }
    }

    if (EPI == 0) {
        // fused rope-reduce epilogue (no V store)
        float cs0=0.f, cs1=0.f, cs2=0.f, cs3=0.f;
        #pragma unroll
        for (int mt=0; mt<4; ++mt) {
            #pragma unroll
            for (int r=0; r<4; ++r) {
                int row = m0 + wm + mt*16 + q*4 + r;
                int ii = (row & 1023) << 6;
                #pragma unroll
                for (int nt=0; nt<4; ++nt) {
                    int col = n0 + wn + nt*16 + r0;
                    float vb = acc[mt][nt][r] + bias[col];
                    float vn = __shfl_xor(vb, 1, 64);
                    float c = w1tp[ii + (col & 63)]*vb + w2tp[ii + (col & 63)]*vn;
                    if (nt == 0) cs0 += c; else if (nt == 1) cs1 += c;
                    else if (nt == 2) cs2 += c; else cs3 += c;
                }
            }
        }
        cs0 += __shfl_xor(cs0, 16, 64); cs0 += __shfl_xor(cs0, 32, 64);
        cs1 += __shfl_xor(cs1, 16, 64); cs1 += __shfl_xor(cs1, 32, 64);
        cs2 += __shfl_xor(cs2, 16, 64); cs2 += __shfl_xor(cs2, 32, 64);
        cs3 += __shfl_xor(cs3, 16, 64); cs3 += __shfl_xor(cs3, 32, 64);
        if (lane < 16) {
            int b = m0 >> 10;
            atomicAdd(&vsump[b*1536 + n0 + wn +  0 + lane], cs0);
            atomicAdd(&vsump[b*1536 + n0 + wn + 16 + lane], cs1);
            atomicAdd(&vsump[b*1536 + n0 + wn + 32 + lane], cs2);
            atomicAdd(&vsump[b*1536 + n0 + wn + 48 + lane], cs3);
        }
    } else {
        #pragma unroll
        for (int mt=0; mt<4; ++mt) {
            #pragma unroll
            for (int nt=0; nt<4; ++nt) {
                int col = n0 + wn + nt*16 + r0;
                #pragma unroll
                for (int r=0; r<4; ++r) {
                    int row = m0 + wm + mt*16 + q*4 + r;
                    float v = acc[mt][nt][r];
                    if (EPI == 3) {
                        o32[(size_t)row*768 + col] = v + bias[(row>>10)*768 + col] + xres[(size_t)row*768 + col];
                    } else {
                        o16[(size_t)row*2304 + 768 + col] = f2b(v);
                    }
                }
            }
        }
    }
}

// ============ mega_prep: all input-independent prep in ONE launch (R7) ============
// Segments (13574 blocks total):
//   [0,1152) Wqkv packs  [1152,3456) W1 pack  [3456,4032) fold1  [4032,4608) pack_bts
//   [4608,9216) cast W2  [9216,9222) pack_bv  [9222,9478) tables/inits  [9478,13574) ln_x
__global__ __launch_bounds__(256) void mega_prep(
    const float* __restrict__ Wqkv, const float* __restrict__ W1,
    const float* __restrict__ Wout, const float* __restrict__ W2,
    const float* __restrict__ ls2,  const float* __restrict__ bqkv,
    const float* __restrict__ x,
    const float* __restrict__ g1, const float* __restrict__ b1v,
    const float* __restrict__ g2, const float* __restrict__ b2v,
    const float* __restrict__ R,  const float* __restrict__ rng,
    const float* __restrict__ rnb, const float* __restrict__ bproj,
    const float* __restrict__ bout,
    ushort* __restrict__ WvT, ushort* __restrict__ W1T, ushort* __restrict__ BTf,
    ushort* __restrict__ Afold, ushort* __restrict__ BT2, float* __restrict__ bvp,
    float* __restrict__ w1t, float* __restrict__ w2t, float* __restrict__ wvec,
    float* __restrict__ attn_c, float* __restrict__ vsum, float* __restrict__ cvecb,
    ushort* __restrict__ xa, ushort* __restrict__ xm, ushort* __restrict__ xc)
{
    __shared__ float tl[32*33];
    const int blk = blockIdx.x;
    const int t = threadIdx.x;

    if (blk < 1152) {
        int p = blk / 576, l = blk % 576;
        int kt = (l % 24)*32, nt = (l / 24)*32;
        const float* src = Wqkv + (size_t)p*768*2304;
        ushort* dst = WvT + (size_t)p*768*768;
        int nl = t & 31, kg = t >> 5;
        #pragma unroll
        for (int kk=0; kk<4; ++kk) {
            int k = kg*4 + kk;
            tl[k*33 + nl] = src[(size_t)(kt + k)*2304 + 1536 + nt + nl];
        }
        __syncthreads();
        int kcol = t & 31, ng = t >> 5;
        #pragma unroll
        for (int nn=0; nn<4; ++nn) {
            int nrow = ng*4 + nn;
            dst[(size_t)(nt + nrow)*768 + kt + kcol] = f2b(tl[kcol*33 + nrow]);
        }
    } else if (blk < 3456) {
        int l = blk - 1152;
        int kt = (l % 24)*32, nt = (l / 24)*32;
        int nl = t & 31, kg = t >> 5;
        #pragma unroll
        for (int kk=0; kk<4; ++kk) {
            int k = kg*4 + kk;
            tl[k*33 + nl] = W1[(size_t)(kt + k)*3072 + nt + nl];
        }
        __syncthreads();
        int kcol = t & 31, ng = t >> 5;
        #pragma unroll
        for (int nn=0; nn<4; ++nn) {
            int nrow = ng*4 + nn;
            W1T[(size_t)(nt + nrow)*768 + kt + kcol] = f2b(tl[kcol*33 + nrow]);
        }
    } else if (blk < 4032) {
        int l = blk - 3456;
        int kt = (l % 24)*32, nt = (l / 24)*32;
        int nl = t & 31, kg = t >> 5;
        #pragma unroll
        for (int kk=0; kk<4; ++kk) {
            int k = kg*4 + kk;
            tl[k*33 + nl] = Wout[(size_t)(kt + k)*768 + nt + nl]
                          + Wout[(size_t)(768 + kt + k)*768 + nt + nl];
        }
        __syncthreads();
        int kcol = t & 31, ng = t >> 5;
        #pragma unroll
        for (int nn=0; nn<4; ++nn) {
            int nrow = ng*4 + nn;
            BTf[(size_t)(nt + nrow)*2304 + kt + kcol] = f2b(tl[kcol*33 + nrow]);
        }
    } else if (blk < 4608) {
        int l = blk - 4032;
        int kt = (l % 24)*32, nt = (l / 24)*32;
        const float* src = Wout + (size_t)768*768;
        int nl = t & 31, kg = t >> 5;
        #pragma unroll
        for (int kk=0; kk<4; ++kk) {
            int k = kg*4 + kk;
            tl[k*33 + nl] = src[(size_t)(kt + k)*768 + nt + nl];
        }
        __syncthreads();
        int kcol = t & 31, ng = t >> 5;
        #pragma unroll
        for (int nn=0; nn<4; ++nn) {
            int nrow = ng*4 + nn;
            Afold[(size_t)(nt + nrow)*768 + kt + kcol] = f2b(tl[kcol*33 + nrow] * ls2[kt + kcol]);
        }
    } else if (blk < 9216) {
        int i = (blk - 4608)*256 + t;
        BT2[i] = f2b(W2[i]);
    } else if (blk < 9222) {
        int i = (blk - 9216)*256 + t;
        if (i < 1536) bvp[i] = bqkv[(i/768)*2304 + 1536 + (i%768)];
    } else if (blk < 9478) {
        int pb = blk - 9222;
        int idx = pb*256 + t;
        {
            int i = idx >> 6, j = idx & 63;
            float w1, w2;
            if (j < 32) {
                int m = j >> 1;
                float inv = powf(10000.f, -(float)m*(1.f/16.f));
                float fr = (float)i * inv;
                float c = cosf(fr), sn = sinf(fr);
                float power = ((float)i - 512.f) * (1.f/512.f);
                float basev = (2.f*(float)(j & 15) + 12.8f) * (1.f/44.8f);
                float sfac = powf(basev, -power);
                w1 = c * sfac;
                w2 = ((j & 1) ? sn : -sn) * sfac;
            } else { w1 = 1.f; w2 = 0.f; }
            w1t[idx] = w1; w2t[idx] = w2;
        }
        if (pb >= 1 && pb <= 12) {
            int k = (pb-1)*256 + t;
            int o = k % 768;
            attn_c[k] = bproj[o] + bproj[768 + o];
        }
        if (pb >= 13 && pb <= 36) {
            int k = (pb-13)*256 + t;
            vsum[k] = 0.f;
        }
        if (pb >= 37 && pb <= 48) {
            int k = (pb-37)*256 + t;
            cvecb[k] = bout[k % 768];
        }
        if (pb == 0) {
            float* mixs = tl;
            float* wsb  = tl + 32;
            if (t < 24) {
                int p = t / 12, g = t % 12;
                float m = 0.f;
                for (int h=0; h<12; ++h) m += R[p*144 + h*12 + g];
                mixs[t] = m;
            }
            __syncthreads();
            if (t < 2) {
                float mean=0.f, var=0.f;
                for (int g=0; g<12; ++g) mean += mixs[t*12+g];
                mean *= (1.f/12.f);
                for (int g=0; g<12; ++g){ float d = mixs[t*12+g]-mean; var += d*d; }
                var *= (1.f/12.f);
                float rstd = rsqrtf(var + 1e-5f);
                for (int g=0; g<12; ++g)
                    wsb[t*12+g] = (mixs[t*12+g]-mean)*rstd*rng[t*12+g] + rnb[t*12+g];
            }
            __syncthreads();
            if (t < 24) wvec[t] = wsb[t];
        }
    } else {
        int row = blk - 9478;
        float* sb = tl;
        float v[3]; float s = 0.f, ss = 0.f;
        #pragma unroll
        for (int e=0; e<3; ++e) { v[e] = x[(size_t)row*768 + t + e*256]; s += v[e]; ss += v[e]*v[e]; }
        for (int o=32; o>0; o>>=1){ s += __shfl_down(s,o,64); ss += __shfl_down(ss,o,64); }
        int lane = t&63, w = t>>6;
        if (lane==0){ sb[w]=s; sb[4+w]=ss; }
        __syncthreads();
        s = sb[0]+sb[1]+sb[2]+sb[3]; ss = sb[4]+sb[5]+sb[6]+sb[7];
        float mean = s*(1.f/768.f);
        float var  = ss*(1.f/768.f) - mean*mean;
        float rstd = rsqrtf(var + 1e-5f);
        #pragma unroll
        for (int e=0; e<3; ++e){
            int c = t + e*256;
            float n = (v[e]-mean)*rstd;
            xa[(size_t)row*768 + c] = f2b(n*g1[c] + b1v[c]);
            xm[(size_t)row*768 + c] = f2b(n*g2[c] + b2v[c]);
            xc[(size_t)row*2304 + c] = f2b(v[e]);
        }
    }
}

// ------- attn_c[b][o] += sum_c (wvec*vsum)[b][c] * Wproj[p][c][o]  (48-chunks, 384 blocks) -------
__global__ __launch_bounds__(256) void attn_gemm(const float* __restrict__ vsum,
    const float* __restrict__ wvec, const float* __restrict__ Wproj, float* __restrict__ attn_c)
{
    int o  = blockIdx.x*256 + threadIdx.x;
    int c0 = blockIdx.y * 48;
    int b  = blockIdx.z;
    int p  = c0 / 768;
    float acc = 0.f;
    #pragma unroll 4
    for (int cc=0; cc<48; ++cc) {
        int c = c0 + cc;
        int cl = c - p*768;
        float y = wvec[p*12 + (cl>>6)] * vsum[b*1536 + c];
        acc += y * Wproj[(size_t)p*589824 + (size_t)cl*768 + o];
    }
    atomicAdd(&attn_c[b*768 + o], acc);
}

// ---- cvecb[b,o] += chunked reduction over 1536 Wout rows (48-chunks, 384 blocks) ----
__global__ __launch_bounds__(256) void cvec_kernel(const float* __restrict__ attn_c,
    const float* __restrict__ ls1, const float* __restrict__ ls2, const float* __restrict__ b2,
    const float* __restrict__ Wout, float* __restrict__ cvecb)
{
    int o  = blockIdx.x*256 + threadIdx.x;
    int r0 = blockIdx.y * 48;
    int b  = blockIdx.z;
    float acc = 0.f;
    #pragma unroll 4
    for (int rr = 0; rr < 48; ++rr) {
        int r = r0 + rr;
        float coef = (r < 768) ? ls1[r]*attn_c[b*768 + r]
                               : ls2[r-768]*b2[r-768];
        acc += coef * Wout[(size_t)r*768 + o];
    }
    atomicAdd(&cvecb[b*768 + o], acc);
}

// ---------------- gate LN stats only: mean/rstd per row -> stats[row] ----------------
__global__ __launch_bounds__(256) void ln_stats(const ushort* __restrict__ xg,
    float2* __restrict__ stats)
{
    __shared__ float sb[8];
    int row = blockIdx.x, t = threadIdx.x;
    float s=0.f, ss=0.f;
    #pragma unroll
    for (int e=0;e<6;++e){ float v = b2f(xg[(size_t)row*1536 + t + e*256]); s+=v; ss+=v*v; }
    for (int o=32; o>0; o>>=1){ s += __shfl_down(s,o,64); ss += __shfl_down(ss,o,64); }
    int lane = t&63, w = t>>6;
    if (lane==0){ sb[w]=s; sb[4+w]=ss; }
    __syncthreads();
    s = sb[0]+sb[1]+sb[2]+sb[3]; ss = sb[4]+sb[5]+sb[6]+sb[7];
    float mean = s*(1.f/1536.f);
    float var  = ss*(1.f/1536.f) - mean*mean;
    if (t == 0) stats[row] = make_float2(mean, rsqrtf(var + 1e-5f));
}

// ------- depthwise conv (K=21) + xr multiply; LN applied inline during staging -------
#define CROWS 128
#define CIN   (CROWS + 20)
#define CSTR  72
__global__ __launch_bounds__(256) void conv_mul(const ushort* __restrict__ xg,
    const float2* __restrict__ stats,
    const float* __restrict__ gg, const float* __restrict__ gb,
    const float* __restrict__ cw, const float* __restrict__ cb,
    const ushort* __restrict__ xr, ushort* __restrict__ u)
{
    __shared__ ushort tile[CIN * CSTR];
    const int c0 = blockIdx.x * 64;
    const int i0 = blockIdx.y * CROWS;
    const int b  = blockIdx.z;
    const int t  = threadIdx.x;
    const size_t base = (size_t)b*1024*1536;

    #pragma unroll
    for (int it = 0; it < 5; ++it) {
        int idx = it*256 + t;
        if (idx < CIN*8) {
            int r  = idx >> 3;
            int cq = (idx & 7) * 8;
            int si = i0 + r - 10;
            uint4 val = make_uint4(0u,0u,0u,0u);
            if (si >= 0 && si < 1024) {
                uint4 raw = *(const uint4*)(xg + base + (size_t)si*1536 + c0 + cq);
                float2 st = stats[b*1024 + si];
                const ushort* rp = (const ushort*)&raw;
                ushort* vp = (ushort*)&val;
                #pragma unroll
                for (int e=0; e<8; ++e) {
                    int c = c0 + cq + e;
                    vp[e] = f2b((b2f(rp[e]) - st.x)*st.y*gg[c] + gb[c]);
                }
            }
            *(uint4*)&tile[r*CSTR + cq] = val;
        }
    }
    __syncthreads();

    const int ch = t & 63;
    const int o0 = (t >> 6) * 32;
    const int c  = c0 + ch;

    float w[21];
    #pragma unroll
    for (int k=0; k<21; ++k) w[k] = cw[c*21 + k];
    const float bias = cb[c];

    float win[21];
    #pragma unroll
    for (int j=0; j<20; ++j) win[j] = b2f(tile[(o0+j)*CSTR + ch]);

    #pragma unroll
    for (int j=0; j<32; ++j) {
        win[(j+20)%21] = b2f(tile[(o0+j+20)*CSTR + ch]);
        float acc = bias;
        #pragma unroll
        for (int k=0; k<21; ++k) acc += win[(j+k)%21] * w[k];
        size_t offr = base + (size_t)(i0+o0+j)*1536 + c;
        u[(size_t)(b*1024 + i0+o0+j)*2304 + 768 + c] = f2b(b2f(xr[offr]) * acc);
    }
}

extern "C" void kernel_launch(void* const* d_in, const int* in_sizes, int n_in,
                              void* d_out, int out_size, void* d_ws, size_t ws_size,
                              hipStream_t stream)
{
    const float* x     = (const float*)d_in[0];
    const float* Wqkv  = (const float*)d_in[1];
    const float* bqkv  = (const float*)d_in[2];
    const float* Wproj = (const float*)d_in[3];
    const float* bproj = (const float*)d_in[4];
    const float* Rw    = (const float*)d_in[9];
    const float* rng   = (const float*)d_in[10];
    const float* rnb   = (const float*)d_in[11];
    const float* ln1g  = (const float*)d_in[12];
    const float* ln1b  = (const float*)d_in[13];
    const float* ln2g  = (const float*)d_in[14];
    const float* ln2b  = (const float*)d_in[15];
    const float* ls1   = (const float*)d_in[16];
    const float* ls2   = (const float*)d_in[17];
    const float* W1    = (const float*)d_in[18];
    const float* b1    = (const float*)d_in[19];
    const float* gng   = (const float*)d_in[20];
    const float* gnb   = (const float*)d_in[21];
    const float* cw    = (const float*)d_in[22];
    const float* cb    = (const float*)d_in[23];
    const float* W2    = (const float*)d_in[24];
    const float* b2    = (const float*)d_in[25];
    const float* Wout  = (const float*)d_in[26];
    const float* bout  = (const float*)d_in[27];
    float* out = (float*)d_out;

    char* ws = (char*)d_ws;
    size_t off = 0;
    auto alloc = [&](size_t bytes)->char* {
        char* p = ws + off;
        off += (bytes + 255) & ~(size_t)255;
        return p;
    };
    ushort* WvT   = (ushort*)alloc(1536*768*2);    // [pc][k]
    ushort* W1T   = (ushort*)alloc(3072*768*2);
    ushort* BT2   = (ushort*)alloc(1536*768*2);    // bf16(W2), [c][d]
    ushort* Afold = (ushort*)alloc(768*768*2);     // ls2[d]*Wout_bot^T, [n][d]
    ushort* BTf   = (ushort*)alloc(768*2304*2);    // folded B^T for final GEMM
    float*  bvp   = (float*)alloc(1536*4);
    float*  w1t   = (float*)alloc(65536*4);
    float*  w2t   = (float*)alloc(65536*4);
    float*  wvec  = (float*)alloc(24*4);
    float*  attnc = (float*)alloc(3072*4);
    float*  vsum  = (float*)alloc(6144*4);
    float*  cvecb = (float*)alloc(3072*4);
    float2* stats = (float2*)alloc(4096*8);
    ushort* xa16  = (ushort*)alloc(4096*768*2);
    ushort* xm16  = (ushort*)alloc(4096*768*2);
    ushort* xr16  = (ushort*)alloc(4096*1536*2);   // GEMM1 left-half output
    ushort* xg16  = (ushort*)alloc(4096*1536*2);
    ushort* xcat  = (ushort*)alloc((size_t)4096*2304*2);  // [bf16(x) | u]
    (void)ws_size; (void)n_in; (void)in_sizes; (void)out_size;

    (void)hipFuncSetAttribute((const void*)gemm256<1>, hipFuncAttributeMaxDynamicSharedMemorySize, 131072);

    // ---- all input-independent prep in ONE launch ----
    mega_prep<<<dim3(13574), 256, 0, stream>>>(
        Wqkv, W1, Wout, W2, ls2, bqkv, x,
        ln1g, ln1b, ln2g, ln2b, Rw, rng, rnb, bproj, bout,
        WvT, W1T, BTf, Afold, BT2, bvp,
        w1t, w2t, wvec, attnc, vsum, cvecb,
        xa16, xm16, xcat);

    // ---- Wfold2: BTf right half = (ls2*Wout_bot)^T @ W2^T ----
    gemm_bf16<4><<<dim3(12, 6), 256, 0, stream>>>(Afold, BT2, 768, 1536, 768, 768, 768,
                                                  nullptr, nullptr, nullptr, nullptr, nullptr,
                                                  BTf, nullptr);

    // ---- V projection with FUSED rope-reduce: vsum += rope-weighted rows; no V store ----
    gemm_bf16<0><<<dim3(12, 32), 256, 0, stream>>>(xa16, WvT, 4096, 1536, 768, 768, 768,
                                                   bvp, nullptr, w1t, w2t, vsum,
                                                   nullptr, nullptr);
    // ---- reattn projection to per-batch constant ----
    attn_gemm<<<dim3(3, 32, 4), 256, 0, stream>>>(vsum, wvec, Wproj, attnc);
    // ---- per-batch output constant ----
    cvec_kernel<<<dim3(3, 32, 4), 256, 0, stream>>>(attnc, ls1, ls2, b2, Wout, cvecb);

    // ---- MLP ----
    gemm256<1><<<dim3(12, 16), 512, 131072, stream>>>(xm16, W1T, 4096, 3072, 768,
                                                      b1, xr16, xg16);
    ln_stats<<<dim3(4096), 256, 0, stream>>>(xg16, stats);
    conv_mul<<<dim3(24, 8, 4), 256, 0, stream>>>(xg16, stats, gng, gnb, cw, cb, xr16, xcat);

    // ---- final fused projection: out = [bf16(x)|u] @ BTf^T + cvecb[b] + x ----
    gemm_bf16<3><<<dim3(6, 32), 256, 0, stream>>>(xcat, BTf, 4096, 768, 2304, 2304, 2304,
                                                  cvecb, x, nullptr, nullptr, nullptr,
                                                  nullptr, out);
}

// Round 11
// 309.880 us; speedup vs baseline: 1.4063x; 1.0047x over previous
//
#include <hip/hip_runtime.h>
#include <hip/hip_bf16.h>

typedef short s16x8 __attribute__((ext_vector_type(8)));
typedef float f32x4 __attribute__((ext_vector_type(4)));

#define C2 1536

__device__ __forceinline__ float b2f(ushort u){ return __uint_as_float(((unsigned)u)<<16); }
__device__ __forceinline__ ushort f2b(float f){ unsigned u = __float_as_uint(f); return (ushort)((u + 0x7fffu + ((u>>16)&1u)) >> 16); }

// async global -> LDS, 16B per lane at wave-uniform LDS base + lane*16
#define GL16(g, l) __builtin_amdgcn_global_load_lds( \
    (const __attribute__((address_space(1))) void*)(g), \
    (__attribute__((address_space(3))) void*)(l), 16, 0, 0)

#define VMW(n) asm volatile("s_waitcnt vmcnt(" #n ")" ::: "memory")
#define LGW()  asm volatile("s_waitcnt lgkmcnt(0)" ::: "memory")
#define SB()   __builtin_amdgcn_sched_barrier(0)
#define BAR()  __builtin_amdgcn_s_barrier()
#define SP1    __builtin_amdgcn_s_setprio(1)
#define SP0    __builtin_amdgcn_s_setprio(0)
#define MF(va, vb, c) __builtin_amdgcn_mfma_f32_16x16x32_bf16(va, vb, c, 0,0,0)

// T1 XCD swizzle (bijective when nwg%8==0, which holds for all grids here: 192/384/192/72).
// Each XCD gets a contiguous row-major chunk of logical tiles -> panel reuse hits its own L2.
__device__ __forceinline__ int xcd_swz(int orig, int nwg) {
    return (orig & 7)*(nwg >> 3) + (orig >> 3);
}

// ======================= 256x256 8-phase bf16 GEMM (verified R3-R10) =======================
// Used only for MLP GEMM1 (M=4096,N=3072,K=768; 192 blocks). See R3 notes.
// R11: + XCD swizzle (FETCH 33.3MB vs 11 ideal = 3x overfetch from cross-XCD panel refetch).
#define RDA(P, mh) { const int ab = (P) + aro + (mh)*4096; \
    a0=L8(ab+sx0);      a1=L8(ab+sx1); \
    a2=L8(ab+1024+sx0); a3=L8(ab+1024+sx1); \
    a4=L8(ab+2048+sx0); a5=L8(ab+2048+sx1); \
    a6=L8(ab+3072+sx0); a7=L8(ab+3072+sx1); }
#define RDB0(P, nh) { const int bb = (P) + bro + (nh)*2048; \
    b00=L8(bb+sx0); b01=L8(bb+sx1); b02=L8(bb+1024+sx0); b03=L8(bb+1024+sx1); }
#define RDB1(P, nh) { const int bb = (P) + bro + (nh)*2048; \
    b10=L8(bb+sx0); b11=L8(bb+sx1); b12=L8(bb+1024+sx0); b13=L8(bb+1024+sx1); }
#define L8(off) (*(const s16x8*)&lds[off])
#define STG(p0, p1, T, dstb) { \
    GL16((p0) + (size_t)(T)*64, &lds[(dstb) + ldsw]); \
    GL16((p1) + (size_t)(T)*64, &lds[(dstb) + 4096 + ldsw]); }
#define QD(mh, nh, B0,B1,B2,B3) { \
  acc[(mh)*4+0][(nh)*2+0]=MF(a0,B0,acc[(mh)*4+0][(nh)*2+0]); \
  acc[(mh)*4+0][(nh)*2+0]=MF(a1,B1,acc[(mh)*4+0][(nh)*2+0]); \
  acc[(mh)*4+0][(nh)*2+1]=MF(a0,B2,acc[(mh)*4+0][(nh)*2+1]); \
  acc[(mh)*4+0][(nh)*2+1]=MF(a1,B3,acc[(mh)*4+0][(nh)*2+1]); \
  acc[(mh)*4+1][(nh)*2+0]=MF(a2,B0,acc[(mh)*4+1][(nh)*2+0]); \
  acc[(mh)*4+1][(nh)*2+0]=MF(a3,B1,acc[(mh)*4+1][(nh)*2+0]); \
  acc[(mh)*4+1][(nh)*2+1]=MF(a2,B2,acc[(mh)*4+1][(nh)*2+1]); \
  acc[(mh)*4+1][(nh)*2+1]=MF(a3,B3,acc[(mh)*4+1][(nh)*2+1]); \
  acc[(mh)*4+2][(nh)*2+0]=MF(a4,B0,acc[(mh)*4+2][(nh)*2+0]); \
  acc[(mh)*4+2][(nh)*2+0]=MF(a5,B1,acc[(mh)*4+2][(nh)*2+0]); \
  acc[(mh)*4+2][(nh)*2+1]=MF(a4,B2,acc[(mh)*4+2][(nh)*2+1]); \
  acc[(mh)*4+2][(nh)*2+1]=MF(a5,B3,acc[(mh)*4+2][(nh)*2+1]); \
  acc[(mh)*4+3][(nh)*2+0]=MF(a6,B0,acc[(mh)*4+3][(nh)*2+0]); \
  acc[(mh)*4+3][(nh)*2+0]=MF(a7,B1,acc[(mh)*4+3][(nh)*2+0]); \
  acc[(mh)*4+3][(nh)*2+1]=MF(a6,B2,acc[(mh)*4+3][(nh)*2+1]); \
  acc[(mh)*4+3][(nh)*2+1]=MF(a7,B3,acc[(mh)*4+3][(nh)*2+1]); }

#define EIGHT(t0, t1, DS, VM4) \
  /*P0*/ VMW(4); BAR(); \
  RDA(0,0); RDB0(0,0); \
  STG(pA00,pA01,(t1), 16384); \
  LGW(); SB(); SP1; QD(0,0,b00,b01,b02,b03); SP0; BAR(); \
  /*P1*/ RDB1(0,1); \
  STG(pA10,pA11,(t1), 24576); \
  BAR(); LGW(); SB(); SP1; QD(0,1,b10,b11,b12,b13); SP0; BAR(); \
  /*P2*/ RDA(0,1); \
  if (DS) { STG(pB00,pB01,(t0)+2, 32768); } \
  BAR(); LGW(); SB(); SP1; QD(1,0,b00,b01,b02,b03); SP0; BAR(); \
  /*P3*/ if (DS) { STG(pB10,pB11,(t0)+2, 40960); } \
  BAR(); SP1; QD(1,1,b10,b11,b12,b13); SP0; BAR(); \
  /*P4*/ VM4; BAR(); \
  RDA(16384,0); RDB0(16384,0); \
  if (DS) { STG(pA00,pA01,(t0)+2, 0); } \
  LGW(); SB(); SP1; QD(0,0,b00,b01,b02,b03); SP0; BAR(); \
  /*P5*/ RDB1(16384,1); \
  if (DS) { STG(pA10,pA11,(t0)+2, 8192); } \
  BAR(); LGW(); SB(); SP1; QD(0,1,b10,b11,b12,b13); SP0; BAR(); \
  /*P6*/ RDA(16384,1); \
  if (DS) { STG(pB00,pB01,(t1)+2, 49152); } \
  BAR(); LGW(); SB(); SP1; QD(1,0,b00,b01,b02,b03); SP0; BAR(); \
  /*P7*/ if (DS) { STG(pB10,pB11,(t1)+2, 57344); } \
  BAR(); SP1; QD(1,1,b10,b11,b12,b13); SP0; BAR();

template<int EPI>
__global__ __launch_bounds__(512, 1) void gemm256(
    const ushort* __restrict__ A, const ushort* __restrict__ BT,
    int M, int N, int K,
    const float* __restrict__ bias,
    ushort* __restrict__ o16, ushort* __restrict__ o16b)
{
    extern __shared__ ushort lds[];
    const int t = threadIdx.x;
    const int lane = t & 63, wv = t >> 6;
    const int wr = wv >> 2, wc = wv & 3;
    const int r0 = lane & 15, q = lane >> 4, e7 = lane & 7;
    const int swz = xcd_swz(blockIdx.y*gridDim.x + blockIdx.x, gridDim.x*gridDim.y);
    const int m0 = (swz / gridDim.x)*256, n0 = (swz % gridDim.x)*256;

    const int idx = wv*64 + lane;
    const int lr8 = idx >> 3;
    const int ksrc = (idx & 7) ^ (lr8 & 7);
    const ushort* pA00 = A  + (size_t)(m0 +   0 +  0 + lr8)*K + ksrc*8;
    const ushort* pA01 = A  + (size_t)(m0 +   0 + 64 + lr8)*K + ksrc*8;
    const ushort* pA10 = A  + (size_t)(m0 + 128 +  0 + lr8)*K + ksrc*8;
    const ushort* pA11 = A  + (size_t)(m0 + 128 + 64 + lr8)*K + ksrc*8;
    const ushort* pB00 = BT + (size_t)(n0 +   0 +  0 + lr8)*K + ksrc*8;
    const ushort* pB01 = BT + (size_t)(n0 +   0 + 64 + lr8)*K + ksrc*8;
    const ushort* pB10 = BT + (size_t)(n0 + 128 +  0 + lr8)*K + ksrc*8;
    const ushort* pB11 = BT + (size_t)(n0 + 128 + 64 + lr8)*K + ksrc*8;
    const int ldsw = wv*512;

    const int aro = (wr*128 + r0)*64;
    const int bro = 32768 + (wc*64 + r0)*64;
    const int sx0 = (q ^ e7)*8, sx1 = ((q ^ e7)*8) ^ 32;

    f32x4 acc[8][4];
    #pragma unroll
    for (int i=0;i<8;++i)
        #pragma unroll
        for (int j=0;j<4;++j) acc[i][j] = (f32x4){0.f,0.f,0.f,0.f};
    s16x8 a0,a1,a2,a3,a4,a5,a6,a7;
    s16x8 b00,b01,b02,b03, b10,b11,b12,b13;

    const int nkt = K >> 6;
    const int niter = nkt >> 1;

    STG(pB00,pB01, 0, 32768);
    STG(pB10,pB11, 0, 40960);
    STG(pA00,pA01, 0, 0);
    STG(pA10,pA11, 0, 8192);
    STG(pB00,pB01, 1, 49152);
    STG(pB10,pB11, 1, 57344);

    for (int i = 0; i < niter-1; ++i) {
        const int t0 = 2*i, t1 = 2*i+1;
        EIGHT(t0, t1, 1, VMW(4));
    }
    {
        const int t0 = nkt-2, t1 = nkt-1;
        EIGHT(t0, t1, 0, VMW(0));
    }

    #pragma unroll
    for (int gm=0; gm<8; ++gm) {
        #pragma unroll
        for (int gn=0; gn<4; ++gn) {
            int col = n0 + wc*64 + gn*16 + r0;
            #pragma unroll
            for (int r=0; r<4; ++r) {
                int row = m0 + wr*128 + gm*16 + q*4 + r;
                float v = acc[gm][gn][r];
                if (EPI == 0) {
                    o16[(size_t)row*N + col] = f2b(v + bias[col]);
                } else {
                    v += bias[col];
                    float g = 0.5f*v*(1.0f + erff(v*0.70710678118f));
                    if (col < C2) o16 [(size_t)row*C2 + col]        = f2b(g);
                    else          o16b[(size_t)row*C2 + (col - C2)] = f2b(g);
                }
            }
        }
    }
}

// ---------------- 128x128 bf16 MFMA GEMM (R0 reg-staged, distance-2 prefetch) ----------------
// R11: + XCD swizzle on the logical tile id (pure index remap, permutation-safe).
// EPI 0: V-projection with FUSED rope-reduce (no V store; math = R0-verified rope_reduce).
// EPI 3: out[row*768+col] = acc + cvecb[(row>>10)*768+col] + x[row*768+col]  (final, fused fold)
// EPI 4: o16[row*2304 + 768 + col] = bf16(acc)                               (Wfold2 -> BTf right)
template<int EPI>
__global__ __launch_bounds__(256) void gemm_bf16(
    const ushort* __restrict__ A, const ushort* __restrict__ BT,
    int M, int N, int K, int lda, int ldbt,
    const float* __restrict__ bias, const float* __restrict__ xres,
    const float* __restrict__ w1tp, const float* __restrict__ w2tp, float* __restrict__ vsump,
    ushort* __restrict__ o16, float* __restrict__ o32)
{
    __shared__ ushort Al[2][128*32];
    __shared__ ushort Bl[2][128*32];
    const int t = threadIdx.x;
    const int swz = xcd_swz(blockIdx.y*gridDim.x + blockIdx.x, gridDim.x*gridDim.y);
    const int m0 = (swz / gridDim.x)*128, n0 = (swz % gridDim.x)*128;
    const int lane = t & 63, wv = t >> 6;
    const int wm = (wv>>1)*64, wn = (wv&1)*64;
    const int r0 = lane & 15, q = lane >> 4;

    const int c0i = t, c1i = t + 256;
    const int lrow0 = ((c0i>>6)<<4) | (c0i&15), lkc0 = ((c0i>>4)&3) << 3;
    const int lrow1 = ((c1i>>6)<<4) | (c1i&15), lkc1 = ((c1i>>4)&3) << 3;
    const ushort* gA0 = A  + (size_t)(m0+lrow0)*lda + lkc0;
    const ushort* gB0 = BT + (size_t)(n0+lrow0)*ldbt + lkc0;
    const ushort* gA1 = A  + (size_t)(m0+lrow1)*lda + lkc1;
    const ushort* gB1 = BT + (size_t)(n0+lrow1)*ldbt + lkc1;

    f32x4 acc[4][4];
    #pragma unroll
    for (int i=0;i<4;++i)
        #pragma unroll
        for (int j=0;j<4;++j) acc[i][j] = (f32x4){0.f,0.f,0.f,0.f};

    const int nkt = K >> 5;
    uint4 pa0_0, pb0_0, pa1_0, pb1_0;
    uint4 pa0_1, pb0_1, pa1_1, pb1_1;
    pa0_0 = *(const uint4*)gA0;        pb0_0 = *(const uint4*)gB0;
    pa1_0 = *(const uint4*)gA1;        pb1_0 = *(const uint4*)gB1;
    pa0_1 = *(const uint4*)(gA0 + 32); pb0_1 = *(const uint4*)(gB0 + 32);
    pa1_1 = *(const uint4*)(gA1 + 32); pb1_1 = *(const uint4*)(gB1 + 32);
    *(uint4*)&Al[0][c0i*8] = pa0_0;
    *(uint4*)&Bl[0][c0i*8] = pb0_0;
    *(uint4*)&Al[0][c1i*8] = pa1_0;
    *(uint4*)&Bl[0][c1i*8] = pb1_0;

    for (int kt = 0; kt < nkt; kt += 2) {
        __syncthreads();
        {
            s16x8 af[4], bfr[4];
            #pragma unroll
            for (int mt=0; mt<4; ++mt) af[mt]  = *(const s16x8*)&Al[0][(((wm>>4)+mt)*64 + lane)*8];
            #pragma unroll
            for (int nt=0; nt<4; ++nt) bfr[nt] = *(const s16x8*)&Bl[0][(((wn>>4)+nt)*64 + lane)*8];
            *(uint4*)&Al[1][c0i*8] = pa0_1;
            *(uint4*)&Bl[1][c0i*8] = pb0_1;
            *(uint4*)&Al[1][c1i*8] = pa1_1;
            *(uint4*)&Bl[1][c1i*8] = pb1_1;
            if (kt+2 < nkt) {
                pa0_0 = *(const uint4*)(gA0 + (kt+2)*32);
                pb0_0 = *(const uint4*)(gB0 + (kt+2)*32);
                pa1_0 = *(const uint4*)(gA1 + (kt+2)*32);
                pb1_0 = *(const uint4*)(gB1 + (kt+2)*32);
            }
            #pragma unroll
            for (int mt=0; mt<4; ++mt)
                #pragma unroll
                for (int nt=0; nt<4; ++nt)
                    acc[mt][nt] = __builtin_amdgcn_mfma_f32_16x16x32_bf16(af[mt], bfr[nt], acc[mt][nt], 0,0,0);
        }
        __syncthreads();
        {
            s16x8 af[4], bfr[4];
            #pragma unroll
            for (int mt=0; mt<4; ++mt) af[mt]  = *(const s16x8*)&Al[1][(((wm>>4)+mt)*64 + lane)*8];
            #pragma unroll
            for (int nt=0; nt<4; ++nt) bfr[nt] = *(const s16x8*)&Bl[1][(((wn>>4)+nt)*64 + lane)*8];
            if (kt+2 < nkt) {
                *(uint4*)&Al[0][c0i*8] = pa0_0;
                *(uint4*)&Bl[0][c0i*8] = pb0_0;
                *(uint4*)&Al[0][c1i*8] = pa1_0;
                *(uint4*)&Bl[0][c1i*8] = pb1_0;
            }
            if (kt+3 < nkt) {
                pa0_1 = *(const uint4*)(gA0 + (kt+3)*32);
                pb0_1 = *(const uint4*)(gB0 + (kt+3)*32);
                pa1_1 = *(const uint4*)(gA1 + (kt+3)*32);
                pb1_1 = *(const uint4*)(gB1 + (kt+3)*32);
            }
            #pragma unroll
            for (int mt=0; mt<4; ++mt)
                #pragma unroll
                for (int nt=0; nt<4; ++nt)
                    acc[mt][nt] = __builtin_amdgcn_mfma_f32_16x16x32_bf16(af[mt], bfr[nt], acc[mt][nt], 0,0,0);
        }
    }

    if (EPI == 0) {
        // fused rope-reduce epilogue (no V store)
        float cs0=0.f, cs1=0.f, cs2=0.f, cs3=0.f;
        #pragma unroll
        for (int mt=0; mt<4; ++mt) {
            #pragma unroll
            for (int r=0; r<4; ++r) {
                int row = m0 + wm + mt*16 + q*4 + r;
                int ii = (row & 1023) << 6;
                #pragma unroll
                for (int nt=0; nt<4; ++nt) {
                    int col = n0 + wn + nt*16 + r0;
                    float vb = acc[mt][nt][r] + bias[col];
                    float vn = __shfl_xor(vb, 1, 64);
                    float c = w1tp[ii + (col & 63)]*vb + w2tp[ii + (col & 63)]*vn;
                    if (nt == 0) cs0 += c; else if (nt == 1) cs1 += c;
                    else if (nt == 2) cs2 += c; else cs3 += c;
                }
            }
        }
        cs0 += __shfl_xor(cs0, 16, 64); cs0 += __shfl_xor(cs0, 32, 64);
        cs1 += __shfl_xor(cs1, 16, 64); cs1 += __shfl_xor(cs1, 32, 64);
        cs2 += __shfl_xor(cs2, 16, 64); cs2 += __shfl_xor(cs2, 32, 64);
        cs3 += __shfl_xor(cs3, 16, 64); cs3 += __shfl_xor(cs3, 32, 64);
        if (lane < 16) {
            int b = m0 >> 10;
            atomicAdd(&vsump[b*1536 + n0 + wn +  0 + lane], cs0);
            atomicAdd(&vsump[b*1536 + n0 + wn + 16 + lane], cs1);
            atomicAdd(&vsump[b*1536 + n0 + wn + 32 + lane], cs2);
            atomicAdd(&vsump[b*1536 + n0 + wn + 48 + lane], cs3);
        }
    } else {
        #pragma unroll
        for (int mt=0; mt<4; ++mt) {
            #pragma unroll
            for (int nt=0; nt<4; ++nt) {
                int col = n0 + wn + nt*16 + r0;
                #pragma unroll
                for (int r=0; r<4; ++r) {
                    int row = m0 + wm + mt*16 + q*4 + r;
                    float v = acc[mt][nt][r];
                    if (EPI == 3) {
                        o32[(size_t)row*768 + col] = v + bias[(row>>10)*768 + col] + xres[(size_t)row*768 + col];
                    } else {
                        o16[(size_t)row*2304 + 768 + col] = f2b(v);
                    }
                }
            }
        }
    }
}

// ============ mega_prep: all input-independent prep in ONE launch (R7) ============
// Segments (13574 blocks total):
//   [0,1152) Wqkv packs  [1152,3456) W1 pack  [3456,4032) fold1  [4032,4608) pack_bts
//   [4608,9216) cast W2  [9216,9222) pack_bv  [9222,9478) tables/inits  [9478,13574) ln_x
__global__ __launch_bounds__(256) void mega_prep(
    const float* __restrict__ Wqkv, const float* __restrict__ W1,
    const float* __restrict__ Wout, const float* __restrict__ W2,
    const float* __restrict__ ls2,  const float* __restrict__ bqkv,
    const float* __restrict__ x,
    const float* __restrict__ g1, const float* __restrict__ b1v,
    const float* __restrict__ g2, const float* __restrict__ b2v,
    const float* __restrict__ R,  const float* __restrict__ rng,
    const float* __restrict__ rnb, const float* __restrict__ bproj,
    const float* __restrict__ bout,
    ushort* __restrict__ WvT, ushort* __restrict__ W1T, ushort* __restrict__ BTf,
    ushort* __restrict__ Afold, ushort* __restrict__ BT2, float* __restrict__ bvp,
    float* __restrict__ w1t, float* __restrict__ w2t, float* __restrict__ wvec,
    float* __restrict__ attn_c, float* __restrict__ vsum, float* __restrict__ cvecb,
    ushort* __restrict__ xa, ushort* __restrict__ xm, ushort* __restrict__ xc)
{
    __shared__ float tl[32*33];
    const int blk = blockIdx.x;
    const int t = threadIdx.x;

    if (blk < 1152) {
        int p = blk / 576, l = blk % 576;
        int kt = (l % 24)*32, nt = (l / 24)*32;
        const float* src = Wqkv + (size_t)p*768*2304;
        ushort* dst = WvT + (size_t)p*768*768;
        int nl = t & 31, kg = t >> 5;
        #pragma unroll
        for (int kk=0; kk<4; ++kk) {
            int k = kg*4 + kk;
            tl[k*33 + nl] = src[(size_t)(kt + k)*2304 + 1536 + nt + nl];
        }
        __syncthreads();
        int kcol = t & 31, ng = t >> 5;
        #pragma unroll
        for (int nn=0; nn<4; ++nn) {
            int nrow = ng*4 + nn;
            dst[(size_t)(nt + nrow)*768 + kt + kcol] = f2b(tl[kcol*33 + nrow]);
        }
    } else if (blk < 3456) {
        int l = blk - 1152;
        int kt = (l % 24)*32, nt = (l / 24)*32;
        int nl = t & 31, kg = t >> 5;
        #pragma unroll
        for (int kk=0; kk<4; ++kk) {
            int k = kg*4 + kk;
            tl[k*33 + nl] = W1[(size_t)(kt + k)*3072 + nt + nl];
        }
        __syncthreads();
        int kcol = t & 31, ng = t >> 5;
        #pragma unroll
        for (int nn=0; nn<4; ++nn) {
            int nrow = ng*4 + nn;
            W1T[(size_t)(nt + nrow)*768 + kt + kcol] = f2b(tl[kcol*33 + nrow]);
        }
    } else if (blk < 4032) {
        int l = blk - 3456;
        int kt = (l % 24)*32, nt = (l / 24)*32;
        int nl = t & 31, kg = t >> 5;
        #pragma unroll
        for (int kk=0; kk<4; ++kk) {
            int k = kg*4 + kk;
            tl[k*33 + nl] = Wout[(size_t)(kt + k)*768 + nt + nl]
                          + Wout[(size_t)(768 + kt + k)*768 + nt + nl];
        }
        __syncthreads();
        int kcol = t & 31, ng = t >> 5;
        #pragma unroll
        for (int nn=0; nn<4; ++nn) {
            int nrow = ng*4 + nn;
            BTf[(size_t)(nt + nrow)*2304 + kt + kcol] = f2b(tl[kcol*33 + nrow]);
        }
    } else if (blk < 4608) {
        int l = blk - 4032;
        int kt = (l % 24)*32, nt = (l / 24)*32;
        const float* src = Wout + (size_t)768*768;
        int nl = t & 31, kg = t >> 5;
        #pragma unroll
        for (int kk=0; kk<4; ++kk) {
            int k = kg*4 + kk;
            tl[k*33 + nl] = src[(size_t)(kt + k)*768 + nt + nl];
        }
        __syncthreads();
        int kcol = t & 31, ng = t >> 5;
        #pragma unroll
        for (int nn=0; nn<4; ++nn) {
            int nrow = ng*4 + nn;
            Afold[(size_t)(nt + nrow)*768 + kt + kcol] = f2b(tl[kcol*33 + nrow] * ls2[kt + kcol]);
        }
    } else if (blk < 9216) {
        int i = (blk - 4608)*256 + t;
        BT2[i] = f2b(W2[i]);
    } else if (blk < 9222) {
        int i = (blk - 9216)*256 + t;
        if (i < 1536) bvp[i] = bqkv[(i/768)*2304 + 1536 + (i%768)];
    } else if (blk < 9478) {
        int pb = blk - 9222;
        int idx = pb*256 + t;
        {
            int i = idx >> 6, j = idx & 63;
            float w1, w2;
            if (j < 32) {
                int m = j >> 1;
                float inv = powf(10000.f, -(float)m*(1.f/16.f));
                float fr = (float)i * inv;
                float c = cosf(fr), sn = sinf(fr);
                float power = ((float)i - 512.f) * (1.f/512.f);
                float basev = (2.f*(float)(j & 15) + 12.8f) * (1.f/44.8f);
                float sfac = powf(basev, -power);
                w1 = c * sfac;
                w2 = ((j & 1) ? sn : -sn) * sfac;
            } else { w1 = 1.f; w2 = 0.f; }
            w1t[idx] = w1; w2t[idx] = w2;
        }
        if (pb >= 1 && pb <= 12) {
            int k = (pb-1)*256 + t;
            int o = k % 768;
            attn_c[k] = bproj[o] + bproj[768 + o];
        }
        if (pb >= 13 && pb <= 36) {
            int k = (pb-13)*256 + t;
            vsum[k] = 0.f;
        }
        if (pb >= 37 && pb <= 48) {
            int k = (pb-37)*256 + t;
            cvecb[k] = bout[k % 768];
        }
        if (pb == 0) {
            float* mixs = tl;
            float* wsb  = tl + 32;
            if (t < 24) {
                int p = t / 12, g = t % 12;
                float m = 0.f;
                for (int h=0; h<12; ++h) m += R[p*144 + h*12 + g];
                mixs[t] = m;
            }
            __syncthreads();
            if (t < 2) {
                float mean=0.f, var=0.f;
                for (int g=0; g<12; ++g) mean += mixs[t*12+g];
                mean *= (1.f/12.f);
                for (int g=0; g<12; ++g){ float d = mixs[t*12+g]-mean; var += d*d; }
                var *= (1.f/12.f);
                float rstd = rsqrtf(var + 1e-5f);
                for (int g=0; g<12; ++g)
                    wsb[t*12+g] = (mixs[t*12+g]-mean)*rstd*rng[t*12+g] + rnb[t*12+g];
            }
            __syncthreads();
            if (t < 24) wvec[t] = wsb[t];
        }
    } else {
        int row = blk - 9478;
        float* sb = tl;
        float v[3]; float s = 0.f, ss = 0.f;
        #pragma unroll
        for (int e=0; e<3; ++e) { v[e] = x[(size_t)row*768 + t + e*256]; s += v[e]; ss += v[e]*v[e]; }
        for (int o=32; o>0; o>>=1){ s += __shfl_down(s,o,64); ss += __shfl_down(ss,o,64); }
        int lane = t&63, w = t>>6;
        if (lane==0){ sb[w]=s; sb[4+w]=ss; }
        __syncthreads();
        s = sb[0]+sb[1]+sb[2]+sb[3]; ss = sb[4]+sb[5]+sb[6]+sb[7];
        float mean = s*(1.f/768.f);
        float var  = ss*(1.f/768.f) - mean*mean;
        float rstd = rsqrtf(var + 1e-5f);
        #pragma unroll
        for (int e=0; e<3; ++e){
            int c = t + e*256;
            float n = (v[e]-mean)*rstd;
            xa[(size_t)row*768 + c] = f2b(n*g1[c] + b1v[c]);
            xm[(size_t)row*768 + c] = f2b(n*g2[c] + b2v[c]);
            xc[(size_t)row*2304 + c] = f2b(v[e]);
        }
    }
}

// ------- attn_c[b][o] += sum_c (wvec*vsum)[b][c] * Wproj[p][c][o]  (48-chunks, 384 blocks) -------
__global__ __launch_bounds__(256) void attn_gemm(const float* __restrict__ vsum,
    const float* __restrict__ wvec, const float* __restrict__ Wproj, float* __restrict__ attn_c)
{
    int o  = blockIdx.x*256 + threadIdx.x;
    int c0 = blockIdx.y * 48;
    int b  = blockIdx.z;
    int p  = c0 / 768;
    float acc = 0.f;
    #pragma unroll 4
    for (int cc=0; cc<48; ++cc) {
        int c = c0 + cc;
        int cl = c - p*768;
        float y = wvec[p*12 + (cl>>6)] * vsum[b*1536 + c];
        acc += y * Wproj[(size_t)p*589824 + (size_t)cl*768 + o];
    }
    atomicAdd(&attn_c[b*768 + o], acc);
}

// ---- cvecb[b,o] += chunked reduction over 1536 Wout rows (48-chunks, 384 blocks) ----
__global__ __launch_bounds__(256) void cvec_kernel(const float* __restrict__ attn_c,
    const float* __restrict__ ls1, const float* __restrict__ ls2, const float* __restrict__ b2,
    const float* __restrict__ Wout, float* __restrict__ cvecb)
{
    int o  = blockIdx.x*256 + threadIdx.x;
    int r0 = blockIdx.y * 48;
    int b  = blockIdx.z;
    float acc = 0.f;
    #pragma unroll 4
    for (int rr = 0; rr < 48; ++rr) {
        int r = r0 + rr;
        float coef = (r < 768) ? ls1[r]*attn_c[b*768 + r]
                               : ls2[r-768]*b2[r-768];
        acc += coef * Wout[(size_t)r*768 + o];
    }
    atomicAdd(&cvecb[b*768 + o], acc);
}

// ---------------- gate LN stats only: mean/rstd per row -> stats[row] ----------------
__global__ __launch_bounds__(256) void ln_stats(const ushort* __restrict__ xg,
    float2* __restrict__ stats)
{
    __shared__ float sb[8];
    int row = blockIdx.x, t = threadIdx.x;
    float s=0.f, ss=0.f;
    #pragma unroll
    for (int e=0;e<6;++e){ float v = b2f(xg[(size_t)row*1536 + t + e*256]); s+=v; ss+=v*v; }
    for (int o=32; o>0; o>>=1){ s += __shfl_down(s,o,64); ss += __shfl_down(ss,o,64); }
    int lane = t&63, w = t>>6;
    if (lane==0){ sb[w]=s; sb[4+w]=ss; }
    __syncthreads();
    s = sb[0]+sb[1]+sb[2]+sb[3]; ss = sb[4]+sb[5]+sb[6]+sb[7];
    float mean = s*(1.f/1536.f);
    float var  = ss*(1.f/1536.f) - mean*mean;
    if (t == 0) stats[row] = make_float2(mean, rsqrtf(var + 1e-5f));
}

// ------- depthwise conv (K=21) + xr multiply; LN applied inline during staging -------
#define CROWS 128
#define CIN   (CROWS + 20)
#define CSTR  72
__global__ __launch_bounds__(256) void conv_mul(const ushort* __restrict__ xg,
    const float2* __restrict__ stats,
    const float* __restrict__ gg, const float* __restrict__ gb,
    const float* __restrict__ cw, const float* __restrict__ cb,
    const ushort* __restrict__ xr, ushort* __restrict__ u)
{
    __shared__ ushort tile[CIN * CSTR];
    const int c0 = blockIdx.x * 64;
    const int i0 = blockIdx.y * CROWS;
    const int b  = blockIdx.z;
    const int t  = threadIdx.x;
    const size_t base = (size_t)b*1024*1536;

    #pragma unroll
    for (int it = 0; it < 5; ++it) {
        int idx = it*256 + t;
        if (idx < CIN*8) {
            int r  = idx >> 3;
            int cq = (idx & 7) * 8;
            int si = i0 + r - 10;
            uint4 val = make_uint4(0u,0u,0u,0u);
            if (si >= 0 && si < 1024) {
                uint4 raw = *(const uint4*)(xg + base + (size_t)si*1536 + c0 + cq);
                float2 st = stats[b*1024 + si];
                const ushort* rp = (const ushort*)&raw;
                ushort* vp = (ushort*)&val;
                #pragma unroll
                for (int e=0; e<8; ++e) {
                    int c = c0 + cq + e;
                    vp[e] = f2b((b2f(rp[e]) - st.x)*st.y*gg[c] + gb[c]);
                }
            }
            *(uint4*)&tile[r*CSTR + cq] = val;
        }
    }
    __syncthreads();

    const int ch = t & 63;
    const int o0 = (t >> 6) * 32;
    const int c  = c0 + ch;

    float w[21];
    #pragma unroll
    for (int k=0; k<21; ++k) w[k] = cw[c*21 + k];
    const float bias = cb[c];

    float win[21];
    #pragma unroll
    for (int j=0; j<20; ++j) win[j] = b2f(tile[(o0+j)*CSTR + ch]);

    #pragma unroll
    for (int j=0; j<32; ++j) {
        win[(j+20)%21] = b2f(tile[(o0+j+20)*CSTR + ch]);
        float acc = bias;
        #pragma unroll
        for (int k=0; k<21; ++k) acc += win[(j+k)%21] * w[k];
        size_t offr = base + (size_t)(i0+o0+j)*1536 + c;
        u[(size_t)(b*1024 + i0+o0+j)*2304 + 768 + c] = f2b(b2f(xr[offr]) * acc);
    }
}

extern "C" void kernel_launch(void* const* d_in, const int* in_sizes, int n_in,
                              void* d_out, int out_size, void* d_ws, size_t ws_size,
                              hipStream_t stream)
{
    const float* x     = (const float*)d_in[0];
    const float* Wqkv  = (const float*)d_in[1];
    const float* bqkv  = (const float*)d_in[2];
    const float* Wproj = (const float*)d_in[3];
    const float* bproj = (const float*)d_in[4];
    const float* Rw    = (const float*)d_in[9];
    const float* rng   = (const float*)d_in[10];
    const float* rnb   = (const float*)d_in[11];
    const float* ln1g  = (const float*)d_in[12];
    const float* ln1b  = (const float*)d_in[13];
    const float* ln2g  = (const float*)d_in[14];
    const float* ln2b  = (const float*)d_in[15];
    const float* ls1   = (const float*)d_in[16];
    const float* ls2   = (const float*)d_in[17];
    const float* W1    = (const float*)d_in[18];
    const float* b1    = (const float*)d_in[19];
    const float* gng   = (const float*)d_in[20];
    const float* gnb   = (const float*)d_in[21];
    const float* cw    = (const float*)d_in[22];
    const float* cb    = (const float*)d_in[23];
    const float* W2    = (const float*)d_in[24];
    const float* b2    = (const float*)d_in[25];
    const float* Wout  = (const float*)d_in[26];
    const float* bout  = (const float*)d_in[27];
    float* out = (float*)d_out;

    char* ws = (char*)d_ws;
    size_t off = 0;
    auto alloc = [&](size_t bytes)->char* {
        char* p = ws + off;
        off += (bytes + 255) & ~(size_t)255;
        return p;
    };
    ushort* WvT   = (ushort*)alloc(1536*768*2);    // [pc][k]
    ushort* W1T   = (ushort*)alloc(3072*768*2);
    ushort* BT2   = (ushort*)alloc(1536*768*2);    // bf16(W2), [c][d]
    ushort* Afold = (ushort*)alloc(768*768*2);     // ls2[d]*Wout_bot^T, [n][d]
    ushort* BTf   = (ushort*)alloc(768*2304*2);    // folded B^T for final GEMM
    float*  bvp   = (float*)alloc(1536*4);
    float*  w1t   = (float*)alloc(65536*4);
    float*  w2t   = (float*)alloc(65536*4);
    float*  wvec  = (float*)alloc(24*4);
    float*  attnc = (float*)alloc(3072*4);
    float*  vsum  = (float*)alloc(6144*4);
    float*  cvecb = (float*)alloc(3072*4);
    float2* stats = (float2*)alloc(4096*8);
    ushort* xa16  = (ushort*)alloc(4096*768*2);
    ushort* xm16  = (ushort*)alloc(4096*768*2);
    ushort* xr16  = (ushort*)alloc(4096*1536*2);   // GEMM1 left-half output
    ushort* xg16  = (ushort*)alloc(4096*1536*2);
    ushort* xcat  = (ushort*)alloc((size_t)4096*2304*2);  // [bf16(x) | u]
    (void)ws_size; (void)n_in; (void)in_sizes; (void)out_size;

    (void)hipFuncSetAttribute((const void*)gemm256<1>, hipFuncAttributeMaxDynamicSharedMemorySize, 131072);

    // ---- all input-independent prep in ONE launch ----
    mega_prep<<<dim3(13574), 256, 0, stream>>>(
        Wqkv, W1, Wout, W2, ls2, bqkv, x,
        ln1g, ln1b, ln2g, ln2b, Rw, rng, rnb, bproj, bout,
        WvT, W1T, BTf, Afold, BT2, bvp,
        w1t, w2t, wvec, attnc, vsum, cvecb,
        xa16, xm16, xcat);

    // ---- Wfold2: BTf right half = (ls2*Wout_bot)^T @ W2^T ----
    gemm_bf16<4><<<dim3(12, 6), 256, 0, stream>>>(Afold, BT2, 768, 1536, 768, 768, 768,
                                                  nullptr, nullptr, nullptr, nullptr, nullptr,
                                                  BTf, nullptr);

    // ---- V projection with FUSED rope-reduce: vsum += rope-weighted rows; no V store ----
    gemm_bf16<0><<<dim3(12, 32), 256, 0, stream>>>(xa16, WvT, 4096, 1536, 768, 768, 768,
                                                   bvp, nullptr, w1t, w2t, vsum,
                                                   nullptr, nullptr);
    // ---- reattn projection to per-batch constant ----
    attn_gemm<<<dim3(3, 32, 4), 256, 0, stream>>>(vsum, wvec, Wproj, attnc);
    // ---- per-batch output constant ----
    cvec_kernel<<<dim3(3, 32, 4), 256, 0, stream>>>(attnc, ls1, ls2, b2, Wout, cvecb);

    // ---- MLP ----
    gemm256<1><<<dim3(12, 16), 512, 131072, stream>>>(xm16, W1T, 4096, 3072, 768,
                                                      b1, xr16, xg16);
    ln_stats<<<dim3(4096), 256, 0, stream>>>(xg16, stats);
    conv_mul<<<dim3(24, 8, 4), 256, 0, stream>>>(xg16, stats, gng, gnb, cw, cb, xr16, xcat);

    // ---- final fused projection: out = [bf16(x)|u] @ BTf^T + cvecb[b] + x ----
    gemm_bf16<3><<<dim3(6, 32), 256, 0, stream>>>(xcat, BTf, 4096, 768, 2304, 2304, 2304,
                                                  cvecb, x, nullptr, nullptr, nullptr,
                                                  nullptr, out);
}